// Round 4
// baseline (245.977 us; speedup 1.0000x reference)
//
#include <hip/hip_runtime.h>
#include <hip/hip_bf16.h>
#include <math.h>

#define D 768
#define HEADS 16
#define DH 48
#define P2 256
#define KSEL 8

// ---------------------------------------------------------------------------
// STAGED PATH kernel 1: depthwise 5x5 conv (pad 2) + BN for q,k,v, fp32.
// Output layout (windowed): [n=b*16+head][win(256)][slot(4)][cc(48)]  fp32
// q is pre-scaled by 768^-0.5. Block: 256 threads = 256 channels (one of 3
// chunks); one (b, row y) per block. Sliding 5x5 register window.
// ---------------------------------------------------------------------------
__global__ __launch_bounds__(256) void conv_qkv(
    const float* __restrict__ x,      // (8,1024,768) fp32
    const float* __restrict__ w,      // (3,768,1,5,5)
    const float* __restrict__ gamma,  // (3,768)
    const float* __restrict__ beta,
    const float* __restrict__ mean,
    const float* __restrict__ var,
    float* __restrict__ qw, float* __restrict__ kw, float* __restrict__ vw)
{
    int bi   = blockIdx.x;            // 8*32*3 = 768 blocks
    int b    = bi / 96;
    int rem  = bi % 96;
    int y    = rem / 3;
    int chunk = rem % 3;
    int c = chunk * 256 + threadIdx.x;

    float wq[25], wk_[25], wv[25];
    const float* wp = w + (size_t)c * 25;
    #pragma unroll
    for (int i = 0; i < 25; i++) wq[i]  = wp[i];
    #pragma unroll
    for (int i = 0; i < 25; i++) wk_[i] = wp[D * 25 + i];
    #pragma unroll
    for (int i = 0; i < 25; i++) wv[i]  = wp[2 * D * 25 + i];

    float invq = gamma[c]       * rsqrtf(var[c]       + 1e-5f);
    float invk = gamma[D + c]   * rsqrtf(var[D + c]   + 1e-5f);
    float invv = gamma[2*D + c] * rsqrtf(var[2*D + c] + 1e-5f);
    float shq = beta[c]       - mean[c]       * invq;
    float shk = beta[D + c]   - mean[D + c]   * invk;
    float shv = beta[2*D + c] - mean[2*D + c] * invv;

    const float scale = 0.03608439182435161f;   // 768^-0.5 folded into q
    invq *= scale; shq *= scale;

    const float* xb = x + (size_t)b * 1024 * D + c;

    float a[5][5];
    bool yok[5];
    #pragma unroll
    for (int i = 0; i < 5; i++) {
        int yy = y - 2 + i;
        yok[i] = (yy >= 0 && yy < 32);
        a[i][0] = 0.f; a[i][1] = 0.f;
        a[i][2] = yok[i] ? xb[(yy * 32 + 0) * D] : 0.f;
        a[i][3] = yok[i] ? xb[(yy * 32 + 1) * D] : 0.f;
        a[i][4] = yok[i] ? xb[(yy * 32 + 2) * D] : 0.f;
    }

    int head = c / DH, cc = c % DH;
    int i0 = y & 15, A = y >> 4;
    int n = b * HEADS + head;

    for (int xx = 0; xx < 32; xx++) {
        float sq = 0.f, sk = 0.f, sv = 0.f;
        #pragma unroll
        for (int i = 0; i < 5; i++)
        #pragma unroll
        for (int j = 0; j < 5; j++) {
            float av = a[i][j];
            sq = fmaf(av, wq[i*5+j],  sq);
            sk = fmaf(av, wk_[i*5+j], sk);
            sv = fmaf(av, wv[i*5+j],  sv);
        }
        int j0 = xx & 15, Bq = xx >> 4;
        int win = i0 * 16 + j0, slot = A * 2 + Bq;
        size_t off = (((size_t)n * P2 + win) * 4 + slot) * DH + cc;
        qw[off] = sq * invq + shq;
        kw[off] = sk * invk + shk;
        vw[off] = sv * invv + shv;
        #pragma unroll
        for (int i = 0; i < 5; i++)
        #pragma unroll
        for (int j = 0; j < 4; j++)
            a[i][j] = a[i][j+1];
        int xn = xx + 3;
        bool xok = (xn < 32);
        #pragma unroll
        for (int i = 0; i < 5; i++) {
            int yy = y - 2 + i;
            a[i][4] = (yok[i] && xok) ? xb[(yy * 32 + xn) * D] : 0.f;
        }
    }
}

// ---------------------------------------------------------------------------
// STAGED PATH kernel 2: fused top-8 + windowed sparse attention.
// One wave per (b,head,window) unit; 4 waves per 256-thread block.
// ---------------------------------------------------------------------------
__global__ __launch_bounds__(256) void topk_attn(
    const float* __restrict__ adjg,   // (128,256,256) fp32
    const float* __restrict__ qw,     // pre-scaled
    const float* __restrict__ kw,
    const float* __restrict__ vw,
    float* __restrict__ out)          // (8,1024,768) fp32
{
    __shared__ float qL[4][192];
    __shared__ float vL[4][32 * 48];
    __shared__ float pL[4][128];

    int wave = threadIdx.x >> 6;
    int lane = threadIdx.x & 63;
    int unit = blockIdx.x * 4 + wave;      // 0..32767
    int n    = unit >> 8;                  // b*16+head
    int win  = unit & 255;
    int b    = n >> 4, head = n & 15;

    float* qs = qL[wave];
    float* vs = vL[wave];
    float* ps = pL[wave];

    // ---- fused top-8 of adj row: one float4 per lane ----
    const float* arow = adjg + ((size_t)n * P2 + win) * P2;
    float4 av4 = *(const float4*)(arow + lane * 4);
    float vals[4] = {av4.x, av4.y, av4.z, av4.w};

    int l2 = lane & 31;
    int kk = l2 >> 2, tt = l2 & 3;
    int mywin = 0;
    #pragma unroll
    for (int it = 0; it < KSEL; it++) {
        float bv = vals[0]; int bidx = lane * 4;
        #pragma unroll
        for (int s = 1; s < 4; s++)
            if (vals[s] > bv) { bv = vals[s]; bidx = lane * 4 + s; }
        #pragma unroll
        for (int m = 32; m >= 1; m >>= 1) {
            float ov = __shfl_xor(bv, m, 64);
            int   oi = __shfl_xor(bidx, m, 64);
            if (ov > bv || (ov == bv && oi < bidx)) { bv = ov; bidx = oi; }
        }
        if (kk == it) mywin = bidx;
        #pragma unroll
        for (int s = 0; s < 4; s++)
            if (lane * 4 + s == bidx) vals[s] = -INFINITY;
    }

    // ---- q into LDS (already scaled) ----
    const float* qp = qw + ((size_t)n * P2 + win) * 192;
    #pragma unroll
    for (int s = 0; s < 3; s++)
        qs[lane + 64 * s] = qp[lane + 64 * s];

    // ---- gather: lanes 0-31 key -> regs; lanes 32-63 value -> LDS ----
    int half = lane >> 5;
    const float* src = (half ? vw : kw) + (((size_t)n * P2 + mywin) * 4 + tt) * DH;
    float kreg[48];
    if (half) {
        #pragma unroll
        for (int c4 = 0; c4 < 12; c4++) {
            float4 t = *(const float4*)(src + c4 * 4);
            vs[l2 * 48 + c4*4 + 0] = t.x;
            vs[l2 * 48 + c4*4 + 1] = t.y;
            vs[l2 * 48 + c4*4 + 2] = t.z;
            vs[l2 * 48 + c4*4 + 3] = t.w;
        }
    } else {
        #pragma unroll
        for (int c4 = 0; c4 < 12; c4++) {
            float4 t = *(const float4*)(src + c4 * 4);
            kreg[c4*4 + 0] = t.x;
            kreg[c4*4 + 1] = t.y;
            kreg[c4*4 + 2] = t.z;
            kreg[c4*4 + 3] = t.w;
        }
    }
    __syncthreads();

    // ---- S = q @ K^T (lanes 0-31, one key each), softmax over 32 keys ----
    if (!half) {
        float s4[4] = {0.f, 0.f, 0.f, 0.f};
        #pragma unroll
        for (int c = 0; c < 48; c++) {
            float kc = kreg[c];
            s4[0] = fmaf(qs[c],       kc, s4[0]);
            s4[1] = fmaf(qs[48 + c],  kc, s4[1]);
            s4[2] = fmaf(qs[96 + c],  kc, s4[2]);
            s4[3] = fmaf(qs[144 + c], kc, s4[3]);
        }
        #pragma unroll
        for (int r = 0; r < 4; r++) {
            float m = s4[r];
            #pragma unroll
            for (int mm = 16; mm >= 1; mm >>= 1)
                m = fmaxf(m, __shfl_xor(m, mm, 64));
            float p = __expf(s4[r] - m);
            float sum = p;
            #pragma unroll
            for (int mm = 16; mm >= 1; mm >>= 1)
                sum += __shfl_xor(sum, mm, 64);
            ps[r * 32 + l2] = p / sum;
        }
    }
    __syncthreads();

    // ---- O = P @ V : 192 outputs, 3/lane; transposed-slot pixel write ----
    int i0 = win >> 4, j0 = win & 15;
    #pragma unroll
    for (int e = 0; e < 3; e++) {
        int idx = lane + 64 * e;
        int r = idx / 48, c = idx % 48;
        float acc = 0.f;
        #pragma unroll
        for (int k2 = 0; k2 < 32; k2++)
            acc = fmaf(ps[r * 32 + k2], vs[k2 * 48 + c], acc);
        int Aq = r >> 1, Bq = r & 1;
        int row = Bq * 16 + i0, col = Aq * 16 + j0;
        out[((size_t)b * 1024 + row * 32 + col) * D + head * DH + c] = acc;
    }
}

// ---------------------------------------------------------------------------
// FUSED PATH (zero workspace): top-8 + inline conv+BN for q and gathered k/v
// + softmax + PV. Used only if ws_size is too small for the staged path.
// ---------------------------------------------------------------------------
__global__ __launch_bounds__(256) void fused_attn(
    const float* __restrict__ x,
    const float* __restrict__ adjg,
    const float* __restrict__ w,
    const float* __restrict__ gamma,
    const float* __restrict__ beta,
    const float* __restrict__ mean,
    const float* __restrict__ var,
    float* __restrict__ out)
{
    __shared__ float wL[3][25][48];
    __shared__ float bnI[3][48], bnS[3][48];
    __shared__ float qL[4][192];
    __shared__ float vL[4][32 * 48];
    __shared__ float pL[4][128];

    int tid  = threadIdx.x;
    int wave = tid >> 6, lane = tid & 63;
    int unit = blockIdx.x * 4 + wave;
    int n    = unit >> 8;                  // block-uniform (4 waves share it)
    int win  = unit & 255;
    int b    = n >> 4, head = n & 15;

    for (int j = tid; j < 3600; j += 256) {
        int chunk = j / 1200, rem = j % 1200, t = rem / 48, cc = rem % 48;
        wL[chunk][t][cc] = w[(size_t)chunk * D * 25 + (head * DH + cc) * 25 + t];
    }
    for (int j = tid; j < 144; j += 256) {
        int chunk = j / 48, cc = j % 48;
        int g = chunk * D + head * DH + cc;
        float inv = gamma[g] * rsqrtf(var[g] + 1e-5f);
        bnI[chunk][cc] = inv;
        bnS[chunk][cc] = beta[g] - mean[g] * inv;
    }
    __syncthreads();

    float* qs = qL[wave];
    float* vs = vL[wave];
    float* ps = pL[wave];

    const float* arow = adjg + ((size_t)n * P2 + win) * P2;
    float4 av4 = *(const float4*)(arow + lane * 4);
    float vals[4] = {av4.x, av4.y, av4.z, av4.w};

    int l2 = lane & 31;
    int kk = l2 >> 2, tt = l2 & 3;
    int mywin = 0;
    #pragma unroll
    for (int it = 0; it < KSEL; it++) {
        float bv = vals[0]; int bidx = lane * 4;
        #pragma unroll
        for (int s = 1; s < 4; s++)
            if (vals[s] > bv) { bv = vals[s]; bidx = lane * 4 + s; }
        #pragma unroll
        for (int m = 32; m >= 1; m >>= 1) {
            float ov = __shfl_xor(bv, m, 64);
            int   oi = __shfl_xor(bidx, m, 64);
            if (ov > bv || (ov == bv && oi < bidx)) { bv = ov; bidx = oi; }
        }
        if (kk == it) mywin = bidx;
        #pragma unroll
        for (int s = 0; s < 4; s++)
            if (lane * 4 + s == bidx) vals[s] = -INFINITY;
    }

    const float scale = 0.03608439182435161f;
    int i0 = win >> 4, j0 = win & 15;
    const float* xbh = x + (size_t)b * 1024 * D + head * DH;

    // q: conv+BN for this window's 4 pixels, 3 (slot,ch) entries per lane
    #pragma unroll
    for (int e = 0; e < 3; e++) {
        int idx = lane + 64 * e;
        int r = idx / 48, cc = idx % 48;
        int yq  = (r >> 1) * 16 + i0;
        int xq0 = (r & 1) * 16 + j0;
        float acc = 0.f;
        for (int ty = 0; ty < 5; ty++) {
            int yy = yq + ty - 2;
            if (yy < 0 || yy > 31) continue;
            for (int tx = 0; tx < 5; tx++) {
                int xx = xq0 + tx - 2;
                if (xx < 0 || xx > 31) continue;
                acc = fmaf(xbh[(size_t)(yy * 32 + xx) * D + cc],
                           wL[0][ty * 5 + tx][cc], acc);
            }
        }
        qs[idx] = (acc * bnI[0][cc] + bnS[0][cc]) * scale;
    }

    // k/v: conv+BN for gathered pixel; lanes 0-31 -> k, 32-63 -> v
    int half  = lane >> 5;
    int chunk = 1 + half;
    float accv[48];
    {
        int yk  = (tt >> 1) * 16 + (mywin >> 4);
        int xk0 = (tt & 1) * 16 + (mywin & 15);
        #pragma unroll
        for (int cc = 0; cc < 48; cc++) accv[cc] = 0.f;
        for (int ty = 0; ty < 5; ty++) {
            int yy = yk + ty - 2;
            if (yy < 0 || yy > 31) continue;
            for (int tx = 0; tx < 5; tx++) {
                int xx = xk0 + tx - 2;
                if (xx < 0 || xx > 31) continue;
                const float* px = xbh + (size_t)(yy * 32 + xx) * D;
                const float* wt = wL[chunk][ty * 5 + tx];
                #pragma unroll
                for (int c4 = 0; c4 < 12; c4++) {
                    float4 xv = *(const float4*)(px + c4 * 4);
                    accv[c4*4+0] = fmaf(xv.x, wt[c4*4+0], accv[c4*4+0]);
                    accv[c4*4+1] = fmaf(xv.y, wt[c4*4+1], accv[c4*4+1]);
                    accv[c4*4+2] = fmaf(xv.z, wt[c4*4+2], accv[c4*4+2]);
                    accv[c4*4+3] = fmaf(xv.w, wt[c4*4+3], accv[c4*4+3]);
                }
            }
        }
        #pragma unroll
        for (int cc = 0; cc < 48; cc++) {
            float val = accv[cc] * bnI[chunk][cc] + bnS[chunk][cc];
            if (half) vs[l2 * 48 + cc] = val;
            else      accv[cc] = val;
        }
    }
    __syncthreads();

    if (!half) {
        float s4[4] = {0.f, 0.f, 0.f, 0.f};
        #pragma unroll
        for (int c = 0; c < 48; c++) {
            float kc = accv[c];
            s4[0] = fmaf(qs[c],       kc, s4[0]);
            s4[1] = fmaf(qs[48 + c],  kc, s4[1]);
            s4[2] = fmaf(qs[96 + c],  kc, s4[2]);
            s4[3] = fmaf(qs[144 + c], kc, s4[3]);
        }
        #pragma unroll
        for (int r = 0; r < 4; r++) {
            float m = s4[r];
            #pragma unroll
            for (int mm = 16; mm >= 1; mm >>= 1)
                m = fmaxf(m, __shfl_xor(m, mm, 64));
            float p = __expf(s4[r] - m);
            float sum = p;
            #pragma unroll
            for (int mm = 16; mm >= 1; mm >>= 1)
                sum += __shfl_xor(sum, mm, 64);
            ps[r * 32 + l2] = p / sum;
        }
    }
    __syncthreads();

    #pragma unroll
    for (int e = 0; e < 3; e++) {
        int idx = lane + 64 * e;
        int r = idx / 48, c = idx % 48;
        float acc = 0.f;
        #pragma unroll
        for (int k2 = 0; k2 < 32; k2++)
            acc = fmaf(ps[r * 32 + k2], vs[k2 * 48 + c], acc);
        int Aq = r >> 1, Bq = r & 1;
        int row = Bq * 16 + i0, col = Aq * 16 + j0;
        out[((size_t)b * 1024 + row * 32 + col) * D + head * DH + c] = acc;
    }
}

extern "C" void kernel_launch(void* const* d_in, const int* in_sizes, int n_in,
                              void* d_out, int out_size, void* d_ws, size_t ws_size,
                              hipStream_t stream)
{
    const float* x     = (const float*)d_in[0];
    // d_in[1] = noise (unused by reference)
    const float* adjg  = (const float*)d_in[2];
    const float* w     = (const float*)d_in[3];
    const float* gamma = (const float*)d_in[4];
    const float* beta  = (const float*)d_in[5];
    const float* mean  = (const float*)d_in[6];
    const float* var   = (const float*)d_in[7];
    // d_in[8] = sparsity (=8, compile-time KSEL)

    const size_t NQKV = (size_t)8 * HEADS * P2 * 4 * DH;   // 6291456 elements
    if (ws_size >= 3 * NQKV * sizeof(float)) {
        float* qw = (float*)d_ws;
        float* kw = qw + NQKV;
        float* vw = kw + NQKV;
        conv_qkv<<<768, 256, 0, stream>>>(x, w, gamma, beta, mean, var,
                                          qw, kw, vw);
        topk_attn<<<8192, 256, 0, stream>>>(adjg, qw, kw, vw, (float*)d_out);
    } else {
        fused_attn<<<8192, 256, 0, stream>>>(x, adjg, w, gamma, beta, mean, var,
                                             (float*)d_out);
    }
}

// Round 5
// 242.163 us; speedup vs baseline: 1.0158x; 1.0158x over previous
//
#include <hip/hip_runtime.h>
#include <hip/hip_bf16.h>
#include <math.h>

#define D 768
#define HEADS 16
#define DH 48
#define P2 256
#define KSEL 8

#define VSTRIDE 49   // pad 48 -> 49: breaks 16-way ds_write bank conflict
#define PSTRIDE 33   // pad 32 -> 33

// ---------------------------------------------------------------------------
// Kernel 1: depthwise 5x5 conv (pad 2) + BN for q,k,v, fp32.
// Output layout (windowed): [n=b*16+head][win(256)][slot(4)][cc(48)]  fp32
// q pre-scaled by 768^-0.5. 256 threads = 256 channels (one of 3 chunks);
// one (b, row y) per block. Sliding 5x5 register window.
// ---------------------------------------------------------------------------
__global__ __launch_bounds__(256) void conv_qkv(
    const float* __restrict__ x,      // (8,1024,768) fp32
    const float* __restrict__ w,      // (3,768,1,5,5)
    const float* __restrict__ gamma,  // (3,768)
    const float* __restrict__ beta,
    const float* __restrict__ mean,
    const float* __restrict__ var,
    float* __restrict__ qw, float* __restrict__ kw, float* __restrict__ vw)
{
    int bi   = blockIdx.x;            // 8*32*3 = 768 blocks
    int b    = bi / 96;
    int rem  = bi % 96;
    int y    = rem / 3;
    int chunk = rem % 3;
    int c = chunk * 256 + threadIdx.x;

    float wq[25], wk_[25], wv[25];
    const float* wp = w + (size_t)c * 25;
    #pragma unroll
    for (int i = 0; i < 25; i++) wq[i]  = wp[i];
    #pragma unroll
    for (int i = 0; i < 25; i++) wk_[i] = wp[D * 25 + i];
    #pragma unroll
    for (int i = 0; i < 25; i++) wv[i]  = wp[2 * D * 25 + i];

    float invq = gamma[c]       * rsqrtf(var[c]       + 1e-5f);
    float invk = gamma[D + c]   * rsqrtf(var[D + c]   + 1e-5f);
    float invv = gamma[2*D + c] * rsqrtf(var[2*D + c] + 1e-5f);
    float shq = beta[c]       - mean[c]       * invq;
    float shk = beta[D + c]   - mean[D + c]   * invk;
    float shv = beta[2*D + c] - mean[2*D + c] * invv;

    const float scale = 0.03608439182435161f;   // 768^-0.5 folded into q
    invq *= scale; shq *= scale;

    const float* xb = x + (size_t)b * 1024 * D + c;

    float a[5][5];
    bool yok[5];
    #pragma unroll
    for (int i = 0; i < 5; i++) {
        int yy = y - 2 + i;
        yok[i] = (yy >= 0 && yy < 32);
        a[i][0] = 0.f; a[i][1] = 0.f;
        a[i][2] = yok[i] ? xb[(yy * 32 + 0) * D] : 0.f;
        a[i][3] = yok[i] ? xb[(yy * 32 + 1) * D] : 0.f;
        a[i][4] = yok[i] ? xb[(yy * 32 + 2) * D] : 0.f;
    }

    int head = c / DH, cc = c % DH;
    int i0 = y & 15, A = y >> 4;
    int n = b * HEADS + head;

    for (int xx = 0; xx < 32; xx++) {
        float sq = 0.f, sk = 0.f, sv = 0.f;
        #pragma unroll
        for (int i = 0; i < 5; i++)
        #pragma unroll
        for (int j = 0; j < 5; j++) {
            float av = a[i][j];
            sq = fmaf(av, wq[i*5+j],  sq);
            sk = fmaf(av, wk_[i*5+j], sk);
            sv = fmaf(av, wv[i*5+j],  sv);
        }
        int j0 = xx & 15, Bq = xx >> 4;
        int win = i0 * 16 + j0, slot = A * 2 + Bq;
        size_t off = (((size_t)n * P2 + win) * 4 + slot) * DH + cc;
        qw[off] = sq * invq + shq;
        kw[off] = sk * invk + shk;
        vw[off] = sv * invv + shv;
        #pragma unroll
        for (int i = 0; i < 5; i++)
        #pragma unroll
        for (int j = 0; j < 4; j++)
            a[i][j] = a[i][j+1];
        int xn = xx + 3;
        bool xok = (xn < 32);
        #pragma unroll
        for (int i = 0; i < 5; i++) {
            int yy = y - 2 + i;
            a[i][4] = (yok[i] && xok) ? xb[(yy * 32 + xn) * D] : 0.f;
        }
    }
}

// ---------------------------------------------------------------------------
// Kernel 2: standalone top-8 over adj rows. BW-bound scan of 134 MB.
// One wave per row; 4 waves/block. Writes 8 int indices per row.
// ---------------------------------------------------------------------------
__global__ __launch_bounds__(256) void topk_idx_kernel(
    const float* __restrict__ adjg,   // (32768, 256)
    int* __restrict__ idxout)         // (32768, 8)
{
    int wave = threadIdx.x >> 6;
    int lane = threadIdx.x & 63;
    int row  = blockIdx.x * 4 + wave;       // 0..32767

    const float* arow = adjg + (size_t)row * P2;
    float4 av4 = *(const float4*)(arow + lane * 4);
    float vals[4] = {av4.x, av4.y, av4.z, av4.w};

    int myidx = 0;
    #pragma unroll
    for (int it = 0; it < KSEL; it++) {
        float bv = vals[0]; int bidx = lane * 4;
        #pragma unroll
        for (int s = 1; s < 4; s++)
            if (vals[s] > bv) { bv = vals[s]; bidx = lane * 4 + s; }
        #pragma unroll
        for (int m = 32; m >= 1; m >>= 1) {
            float ov = __shfl_xor(bv, m, 64);
            int   oi = __shfl_xor(bidx, m, 64);
            if (ov > bv || (ov == bv && oi < bidx)) { bv = ov; bidx = oi; }
        }
        if (lane == it) myidx = bidx;        // lane `it` keeps winner `it`
        #pragma unroll
        for (int s = 0; s < 4; s++)
            if (lane * 4 + s == bidx) vals[s] = -INFINITY;
    }
    if (lane < KSEL)
        idxout[row * KSEL + lane] = myidx;
}

// ---------------------------------------------------------------------------
// Kernel 3: windowed sparse attention from precomputed indices.
// One wave per (b,head,window) unit; 4 waves per 256-thread block.
// ---------------------------------------------------------------------------
__global__ __launch_bounds__(256) void attn_kernel(
    const int*   __restrict__ idxin,  // (32768, 8)
    const float* __restrict__ qw,     // pre-scaled
    const float* __restrict__ kw,
    const float* __restrict__ vw,
    float* __restrict__ out)          // (8,1024,768) fp32
{
    __shared__ float qL[4][192];
    __shared__ float vL[4][32 * VSTRIDE];
    __shared__ float pL[4][4 * PSTRIDE];

    int wave = threadIdx.x >> 6;
    int lane = threadIdx.x & 63;
    int row  = blockIdx.x * 4 + wave;      // 0..32767
    int n    = row >> 8;                   // b*16+head
    int win  = row & 255;
    int b    = n >> 4, head = n & 15;

    float* qs = qL[wave];
    float* vs = vL[wave];
    float* ps = pL[wave];

    int l2 = lane & 31;
    int kk = l2 >> 2, tt = l2 & 3;
    int mywin = idxin[row * KSEL + kk];

    // ---- q into LDS (already scaled) ----
    const float* qp = qw + ((size_t)n * P2 + win) * 192;
    #pragma unroll
    for (int s = 0; s < 3; s++)
        qs[lane + 64 * s] = qp[lane + 64 * s];

    // ---- gather: lanes 0-31 key -> regs; lanes 32-63 value -> LDS ----
    int half = lane >> 5;
    const float* src = (half ? vw : kw) + (((size_t)n * P2 + mywin) * 4 + tt) * DH;
    float kreg[48];
    if (half) {
        #pragma unroll
        for (int c4 = 0; c4 < 12; c4++) {
            float4 t = *(const float4*)(src + c4 * 4);
            float* dst = vs + l2 * VSTRIDE + c4 * 4;
            dst[0] = t.x; dst[1] = t.y; dst[2] = t.z; dst[3] = t.w;
        }
    } else {
        #pragma unroll
        for (int c4 = 0; c4 < 12; c4++) {
            float4 t = *(const float4*)(src + c4 * 4);
            kreg[c4*4 + 0] = t.x;
            kreg[c4*4 + 1] = t.y;
            kreg[c4*4 + 2] = t.z;
            kreg[c4*4 + 3] = t.w;
        }
    }
    __syncthreads();

    // ---- S = q @ K^T (lanes 0-31, one key each), softmax over 32 keys ----
    if (!half) {
        float s4[4] = {0.f, 0.f, 0.f, 0.f};
        #pragma unroll
        for (int c = 0; c < 48; c++) {
            float kc = kreg[c];
            s4[0] = fmaf(qs[c],       kc, s4[0]);
            s4[1] = fmaf(qs[48 + c],  kc, s4[1]);
            s4[2] = fmaf(qs[96 + c],  kc, s4[2]);
            s4[3] = fmaf(qs[144 + c], kc, s4[3]);
        }
        #pragma unroll
        for (int r = 0; r < 4; r++) {
            float m = s4[r];
            #pragma unroll
            for (int mm = 16; mm >= 1; mm >>= 1)
                m = fmaxf(m, __shfl_xor(m, mm, 64));
            float p = __expf(s4[r] - m);
            float sum = p;
            #pragma unroll
            for (int mm = 16; mm >= 1; mm >>= 1)
                sum += __shfl_xor(sum, mm, 64);
            ps[r * PSTRIDE + l2] = p / sum;
        }
    }
    __syncthreads();

    // ---- O = P @ V : 192 outputs, 3/lane; transposed-slot pixel write ----
    int i0 = win >> 4, j0 = win & 15;
    #pragma unroll
    for (int e = 0; e < 3; e++) {
        int idx = lane + 64 * e;
        int r = idx / 48, c = idx % 48;
        float acc = 0.f;
        #pragma unroll
        for (int k2 = 0; k2 < 32; k2++)
            acc = fmaf(ps[r * PSTRIDE + k2], vs[k2 * VSTRIDE + c], acc);
        int Aq = r >> 1, Bq = r & 1;
        int rowp = Bq * 16 + i0, colp = Aq * 16 + j0;
        out[((size_t)b * 1024 + rowp * 32 + colp) * D + head * DH + c] = acc;
    }
}

// ---------------------------------------------------------------------------
// Fallback A (ws >= 75.5MB only): fused top-8 + attention (round-4 version).
// ---------------------------------------------------------------------------
__global__ __launch_bounds__(256) void topk_attn(
    const float* __restrict__ adjg,
    const float* __restrict__ qw,
    const float* __restrict__ kw,
    const float* __restrict__ vw,
    float* __restrict__ out)
{
    __shared__ float qL[4][192];
    __shared__ float vL[4][32 * VSTRIDE];
    __shared__ float pL[4][4 * PSTRIDE];

    int wave = threadIdx.x >> 6;
    int lane = threadIdx.x & 63;
    int unit = blockIdx.x * 4 + wave;
    int n    = unit >> 8;
    int win  = unit & 255;
    int b    = n >> 4, head = n & 15;

    float* qs = qL[wave];
    float* vs = vL[wave];
    float* ps = pL[wave];

    const float* arow = adjg + ((size_t)n * P2 + win) * P2;
    float4 av4 = *(const float4*)(arow + lane * 4);
    float vals[4] = {av4.x, av4.y, av4.z, av4.w};

    int l2 = lane & 31;
    int kk = l2 >> 2, tt = l2 & 3;
    int mywin = 0;
    #pragma unroll
    for (int it = 0; it < KSEL; it++) {
        float bv = vals[0]; int bidx = lane * 4;
        #pragma unroll
        for (int s = 1; s < 4; s++)
            if (vals[s] > bv) { bv = vals[s]; bidx = lane * 4 + s; }
        #pragma unroll
        for (int m = 32; m >= 1; m >>= 1) {
            float ov = __shfl_xor(bv, m, 64);
            int   oi = __shfl_xor(bidx, m, 64);
            if (ov > bv || (ov == bv && oi < bidx)) { bv = ov; bidx = oi; }
        }
        if (kk == it) mywin = bidx;
        #pragma unroll
        for (int s = 0; s < 4; s++)
            if (lane * 4 + s == bidx) vals[s] = -INFINITY;
    }

    const float* qp = qw + ((size_t)n * P2 + win) * 192;
    #pragma unroll
    for (int s = 0; s < 3; s++)
        qs[lane + 64 * s] = qp[lane + 64 * s];

    int half = lane >> 5;
    const float* src = (half ? vw : kw) + (((size_t)n * P2 + mywin) * 4 + tt) * DH;
    float kreg[48];
    if (half) {
        #pragma unroll
        for (int c4 = 0; c4 < 12; c4++) {
            float4 t = *(const float4*)(src + c4 * 4);
            float* dst = vs + l2 * VSTRIDE + c4 * 4;
            dst[0] = t.x; dst[1] = t.y; dst[2] = t.z; dst[3] = t.w;
        }
    } else {
        #pragma unroll
        for (int c4 = 0; c4 < 12; c4++) {
            float4 t = *(const float4*)(src + c4 * 4);
            kreg[c4*4 + 0] = t.x;
            kreg[c4*4 + 1] = t.y;
            kreg[c4*4 + 2] = t.z;
            kreg[c4*4 + 3] = t.w;
        }
    }
    __syncthreads();

    if (!half) {
        float s4[4] = {0.f, 0.f, 0.f, 0.f};
        #pragma unroll
        for (int c = 0; c < 48; c++) {
            float kc = kreg[c];
            s4[0] = fmaf(qs[c],       kc, s4[0]);
            s4[1] = fmaf(qs[48 + c],  kc, s4[1]);
            s4[2] = fmaf(qs[96 + c],  kc, s4[2]);
            s4[3] = fmaf(qs[144 + c], kc, s4[3]);
        }
        #pragma unroll
        for (int r = 0; r < 4; r++) {
            float m = s4[r];
            #pragma unroll
            for (int mm = 16; mm >= 1; mm >>= 1)
                m = fmaxf(m, __shfl_xor(m, mm, 64));
            float p = __expf(s4[r] - m);
            float sum = p;
            #pragma unroll
            for (int mm = 16; mm >= 1; mm >>= 1)
                sum += __shfl_xor(sum, mm, 64);
            ps[r * PSTRIDE + l2] = p / sum;
        }
    }
    __syncthreads();

    int i0 = win >> 4, j0 = win & 15;
    #pragma unroll
    for (int e = 0; e < 3; e++) {
        int idx = lane + 64 * e;
        int r = idx / 48, c = idx % 48;
        float acc = 0.f;
        #pragma unroll
        for (int k2 = 0; k2 < 32; k2++)
            acc = fmaf(ps[r * PSTRIDE + k2], vs[k2 * VSTRIDE + c], acc);
        int Aq = r >> 1, Bq = r & 1;
        int rowp = Bq * 16 + i0, colp = Aq * 16 + j0;
        out[((size_t)b * 1024 + rowp * 32 + colp) * D + head * DH + c] = acc;
    }
}

// ---------------------------------------------------------------------------
// Fallback B (zero workspace): fully fused, round-3 version.
// ---------------------------------------------------------------------------
__global__ __launch_bounds__(256) void fused_attn(
    const float* __restrict__ x,
    const float* __restrict__ adjg,
    const float* __restrict__ w,
    const float* __restrict__ gamma,
    const float* __restrict__ beta,
    const float* __restrict__ mean,
    const float* __restrict__ var,
    float* __restrict__ out)
{
    __shared__ float wL[3][25][48];
    __shared__ float bnI[3][48], bnS[3][48];
    __shared__ float qL[4][192];
    __shared__ float vL[4][32 * VSTRIDE];
    __shared__ float pL[4][4 * PSTRIDE];

    int tid  = threadIdx.x;
    int wave = tid >> 6, lane = tid & 63;
    int unit = blockIdx.x * 4 + wave;
    int n    = unit >> 8;
    int win  = unit & 255;
    int b    = n >> 4, head = n & 15;

    for (int j = tid; j < 3600; j += 256) {
        int chunk = j / 1200, rem = j % 1200, t = rem / 48, cc = rem % 48;
        wL[chunk][t][cc] = w[(size_t)chunk * D * 25 + (head * DH + cc) * 25 + t];
    }
    for (int j = tid; j < 144; j += 256) {
        int chunk = j / 48, cc = j % 48;
        int g = chunk * D + head * DH + cc;
        float inv = gamma[g] * rsqrtf(var[g] + 1e-5f);
        bnI[chunk][cc] = inv;
        bnS[chunk][cc] = beta[g] - mean[g] * inv;
    }
    __syncthreads();

    float* qs = qL[wave];
    float* vs = vL[wave];
    float* ps = pL[wave];

    const float* arow = adjg + ((size_t)n * P2 + win) * P2;
    float4 av4 = *(const float4*)(arow + lane * 4);
    float vals[4] = {av4.x, av4.y, av4.z, av4.w};

    int l2 = lane & 31;
    int kk = l2 >> 2, tt = l2 & 3;
    int mywin = 0;
    #pragma unroll
    for (int it = 0; it < KSEL; it++) {
        float bv = vals[0]; int bidx = lane * 4;
        #pragma unroll
        for (int s = 1; s < 4; s++)
            if (vals[s] > bv) { bv = vals[s]; bidx = lane * 4 + s; }
        #pragma unroll
        for (int m = 32; m >= 1; m >>= 1) {
            float ov = __shfl_xor(bv, m, 64);
            int   oi = __shfl_xor(bidx, m, 64);
            if (ov > bv || (ov == bv && oi < bidx)) { bv = ov; bidx = oi; }
        }
        if (kk == it) mywin = bidx;
        #pragma unroll
        for (int s = 0; s < 4; s++)
            if (lane * 4 + s == bidx) vals[s] = -INFINITY;
    }

    const float scale = 0.03608439182435161f;
    int i0 = win >> 4, j0 = win & 15;
    const float* xbh = x + (size_t)b * 1024 * D + head * DH;

    #pragma unroll
    for (int e = 0; e < 3; e++) {
        int idx = lane + 64 * e;
        int r = idx / 48, cc = idx % 48;
        int yq  = (r >> 1) * 16 + i0;
        int xq0 = (r & 1) * 16 + j0;
        float acc = 0.f;
        for (int ty = 0; ty < 5; ty++) {
            int yy = yq + ty - 2;
            if (yy < 0 || yy > 31) continue;
            for (int tx = 0; tx < 5; tx++) {
                int xx = xq0 + tx - 2;
                if (xx < 0 || xx > 31) continue;
                acc = fmaf(xbh[(size_t)(yy * 32 + xx) * D + cc],
                           wL[0][ty * 5 + tx][cc], acc);
            }
        }
        qs[idx] = (acc * bnI[0][cc] + bnS[0][cc]) * scale;
    }

    int half  = lane >> 5;
    int chunk = 1 + half;
    float accv[48];
    {
        int yk  = (tt >> 1) * 16 + (mywin >> 4);
        int xk0 = (tt & 1) * 16 + (mywin & 15);
        #pragma unroll
        for (int cc = 0; cc < 48; cc++) accv[cc] = 0.f;
        for (int ty = 0; ty < 5; ty++) {
            int yy = yk + ty - 2;
            if (yy < 0 || yy > 31) continue;
            for (int tx = 0; tx < 5; tx++) {
                int xx = xk0 + tx - 2;
                if (xx < 0 || xx > 31) continue;
                const float* px = xbh + (size_t)(yy * 32 + xx) * D;
                const float* wt = wL[chunk][ty * 5 + tx];
                #pragma unroll
                for (int c4 = 0; c4 < 12; c4++) {
                    float4 xv = *(const float4*)(px + c4 * 4);
                    accv[c4*4+0] = fmaf(xv.x, wt[c4*4+0], accv[c4*4+0]);
                    accv[c4*4+1] = fmaf(xv.y, wt[c4*4+1], accv[c4*4+1]);
                    accv[c4*4+2] = fmaf(xv.z, wt[c4*4+2], accv[c4*4+2]);
                    accv[c4*4+3] = fmaf(xv.w, wt[c4*4+3], accv[c4*4+3]);
                }
            }
        }
        #pragma unroll
        for (int cc = 0; cc < 48; cc++) {
            float val = accv[cc] * bnI[chunk][cc] + bnS[chunk][cc];
            if (half) vs[l2 * VSTRIDE + cc] = val;
            else      accv[cc] = val;
        }
    }
    __syncthreads();

    if (!half) {
        float s4[4] = {0.f, 0.f, 0.f, 0.f};
        #pragma unroll
        for (int c = 0; c < 48; c++) {
            float kc = accv[c];
            s4[0] = fmaf(qs[c],       kc, s4[0]);
            s4[1] = fmaf(qs[48 + c],  kc, s4[1]);
            s4[2] = fmaf(qs[96 + c],  kc, s4[2]);
            s4[3] = fmaf(qs[144 + c], kc, s4[3]);
        }
        #pragma unroll
        for (int r = 0; r < 4; r++) {
            float m = s4[r];
            #pragma unroll
            for (int mm = 16; mm >= 1; mm >>= 1)
                m = fmaxf(m, __shfl_xor(m, mm, 64));
            float p = __expf(s4[r] - m);
            float sum = p;
            #pragma unroll
            for (int mm = 16; mm >= 1; mm >>= 1)
                sum += __shfl_xor(sum, mm, 64);
            ps[r * PSTRIDE + l2] = p / sum;
        }
    }
    __syncthreads();

    #pragma unroll
    for (int e = 0; e < 3; e++) {
        int idx = lane + 64 * e;
        int r = idx / 48, c = idx % 48;
        float acc = 0.f;
        #pragma unroll
        for (int k2 = 0; k2 < 32; k2++)
            acc = fmaf(ps[r * PSTRIDE + k2], vs[k2 * VSTRIDE + c], acc);
        int Aq = r >> 1, Bq = r & 1;
        int rowp = Bq * 16 + i0, colp = Aq * 16 + j0;
        out[((size_t)b * 1024 + rowp * 32 + colp) * D + head * DH + c] = acc;
    }
}

extern "C" void kernel_launch(void* const* d_in, const int* in_sizes, int n_in,
                              void* d_out, int out_size, void* d_ws, size_t ws_size,
                              hipStream_t stream)
{
    const float* x     = (const float*)d_in[0];
    // d_in[1] = noise (unused by reference)
    const float* adjg  = (const float*)d_in[2];
    const float* w     = (const float*)d_in[3];
    const float* gamma = (const float*)d_in[4];
    const float* beta  = (const float*)d_in[5];
    const float* mean  = (const float*)d_in[6];
    const float* var   = (const float*)d_in[7];
    // d_in[8] = sparsity (=8, compile-time KSEL)

    const size_t NQKV   = (size_t)8 * HEADS * P2 * 4 * DH;   // 6291456 elements
    const size_t NROWS  = (size_t)8 * HEADS * P2;            // 32768
    const size_t need2  = 3 * NQKV * sizeof(float);
    const size_t need3  = need2 + NROWS * KSEL * sizeof(int);

    if (ws_size >= need3) {
        float* qw  = (float*)d_ws;
        float* kw  = qw + NQKV;
        float* vw  = kw + NQKV;
        int*   idx = (int*)(vw + NQKV);
        conv_qkv<<<768, 256, 0, stream>>>(x, w, gamma, beta, mean, var,
                                          qw, kw, vw);
        topk_idx_kernel<<<8192, 256, 0, stream>>>(adjg, idx);
        attn_kernel<<<8192, 256, 0, stream>>>(idx, qw, kw, vw, (float*)d_out);
    } else if (ws_size >= need2) {
        float* qw = (float*)d_ws;
        float* kw = qw + NQKV;
        float* vw = kw + NQKV;
        conv_qkv<<<768, 256, 0, stream>>>(x, w, gamma, beta, mean, var,
                                          qw, kw, vw);
        topk_attn<<<8192, 256, 0, stream>>>(adjg, qw, kw, vw, (float*)d_out);
    } else {
        fused_attn<<<8192, 256, 0, stream>>>(x, adjg, w, gamma, beta, mean, var,
                                             (float*)d_out);
    }
}

// Round 6
// 231.093 us; speedup vs baseline: 1.0644x; 1.0479x over previous
//
#include <hip/hip_runtime.h>
#include <hip/hip_bf16.h>
#include <math.h>

#define D 768
#define HEADS 16
#define DH 48
#define P2 256
#define KSEL 8

#define VSTRIDE 49   // (fallback kernels) pad 48 -> 49
#define PSTRIDE 33   // (fallback kernels) pad 32 -> 33

// ---------------------------------------------------------------------------
// Kernel 1: depthwise 5x5 conv (pad 2) + BN for q,k,v, fp32.
// Output layout (windowed): [n=b*16+head][win(256)][slot(4)][cc(48)]  fp32
// q pre-scaled by 768^-0.5.
// ---------------------------------------------------------------------------
__global__ __launch_bounds__(256) void conv_qkv(
    const float* __restrict__ x,      // (8,1024,768) fp32
    const float* __restrict__ w,      // (3,768,1,5,5)
    const float* __restrict__ gamma,  // (3,768)
    const float* __restrict__ beta,
    const float* __restrict__ mean,
    const float* __restrict__ var,
    float* __restrict__ qw, float* __restrict__ kw, float* __restrict__ vw)
{
    int bi   = blockIdx.x;            // 8*32*3 = 768 blocks
    int b    = bi / 96;
    int rem  = bi % 96;
    int y    = rem / 3;
    int chunk = rem % 3;
    int c = chunk * 256 + threadIdx.x;

    float wq[25], wk_[25], wv[25];
    const float* wp = w + (size_t)c * 25;
    #pragma unroll
    for (int i = 0; i < 25; i++) wq[i]  = wp[i];
    #pragma unroll
    for (int i = 0; i < 25; i++) wk_[i] = wp[D * 25 + i];
    #pragma unroll
    for (int i = 0; i < 25; i++) wv[i]  = wp[2 * D * 25 + i];

    float invq = gamma[c]       * rsqrtf(var[c]       + 1e-5f);
    float invk = gamma[D + c]   * rsqrtf(var[D + c]   + 1e-5f);
    float invv = gamma[2*D + c] * rsqrtf(var[2*D + c] + 1e-5f);
    float shq = beta[c]       - mean[c]       * invq;
    float shk = beta[D + c]   - mean[D + c]   * invk;
    float shv = beta[2*D + c] - mean[2*D + c] * invv;

    const float scale = 0.03608439182435161f;   // 768^-0.5 folded into q
    invq *= scale; shq *= scale;

    const float* xb = x + (size_t)b * 1024 * D + c;

    float a[5][5];
    bool yok[5];
    #pragma unroll
    for (int i = 0; i < 5; i++) {
        int yy = y - 2 + i;
        yok[i] = (yy >= 0 && yy < 32);
        a[i][0] = 0.f; a[i][1] = 0.f;
        a[i][2] = yok[i] ? xb[(yy * 32 + 0) * D] : 0.f;
        a[i][3] = yok[i] ? xb[(yy * 32 + 1) * D] : 0.f;
        a[i][4] = yok[i] ? xb[(yy * 32 + 2) * D] : 0.f;
    }

    int head = c / DH, cc = c % DH;
    int i0 = y & 15, A = y >> 4;
    int n = b * HEADS + head;

    for (int xx = 0; xx < 32; xx++) {
        float sq = 0.f, sk = 0.f, sv = 0.f;
        #pragma unroll
        for (int i = 0; i < 5; i++)
        #pragma unroll
        for (int j = 0; j < 5; j++) {
            float av = a[i][j];
            sq = fmaf(av, wq[i*5+j],  sq);
            sk = fmaf(av, wk_[i*5+j], sk);
            sv = fmaf(av, wv[i*5+j],  sv);
        }
        int j0 = xx & 15, Bq = xx >> 4;
        int win = i0 * 16 + j0, slot = A * 2 + Bq;
        size_t off = (((size_t)n * P2 + win) * 4 + slot) * DH + cc;
        qw[off] = sq * invq + shq;
        kw[off] = sk * invk + shk;
        vw[off] = sv * invv + shv;
        #pragma unroll
        for (int i = 0; i < 5; i++)
        #pragma unroll
        for (int j = 0; j < 4; j++)
            a[i][j] = a[i][j+1];
        int xn = xx + 3;
        bool xok = (xn < 32);
        #pragma unroll
        for (int i = 0; i < 5; i++) {
            int yy = y - 2 + i;
            a[i][4] = (yok[i] && xok) ? xb[(yy * 32 + xn) * D] : 0.f;
        }
    }
}

// ---------------------------------------------------------------------------
// Kernel 2: standalone top-8 over adj rows. BW-bound scan of 134 MB.
// ---------------------------------------------------------------------------
__global__ __launch_bounds__(256) void topk_idx_kernel(
    const float* __restrict__ adjg,   // (32768, 256)
    int* __restrict__ idxout)         // (32768, 8)
{
    int wave = threadIdx.x >> 6;
    int lane = threadIdx.x & 63;
    int row  = blockIdx.x * 4 + wave;       // 0..32767

    const float* arow = adjg + (size_t)row * P2;
    float4 av4 = *(const float4*)(arow + lane * 4);
    float vals[4] = {av4.x, av4.y, av4.z, av4.w};

    int myidx = 0;
    #pragma unroll
    for (int it = 0; it < KSEL; it++) {
        float bv = vals[0]; int bidx = lane * 4;
        #pragma unroll
        for (int s = 1; s < 4; s++)
            if (vals[s] > bv) { bv = vals[s]; bidx = lane * 4 + s; }
        #pragma unroll
        for (int m = 32; m >= 1; m >>= 1) {
            float ov = __shfl_xor(bv, m, 64);
            int   oi = __shfl_xor(bidx, m, 64);
            if (ov > bv || (ov == bv && oi < bidx)) { bv = ov; bidx = oi; }
        }
        if (lane == it) myidx = bidx;
        #pragma unroll
        for (int s = 0; s < 4; s++)
            if (lane * 4 + s == bidx) vals[s] = -INFINITY;
    }
    if (lane < KSEL)
        idxout[row * KSEL + lane] = myidx;
}

// ---------------------------------------------------------------------------
// Kernel 3: attention with float4 LDS layout + XCD-locality swizzle.
// One wave per (n,win); 4 waves/block; all 4 waves share n.
// LDS/wave: vs4[32][13] f4 + qs4[4][13] f4 + ps[4][36] f  = 8064 B
//   (f4-stride 13 keeps reads <=2-way-conflicted; total 32256 B -> 5 blk/CU)
// ---------------------------------------------------------------------------
__global__ __launch_bounds__(256) void attn_kernel(
    const int*   __restrict__ idxin,  // (32768, 8)
    const float* __restrict__ qw,     // pre-scaled
    const float* __restrict__ kw,
    const float* __restrict__ vw,
    float* __restrict__ out)          // (8,1024,768) fp32
{
    __shared__ float4 vL[4][32 * 13];
    __shared__ float4 qL[4][4 * 13];
    __shared__ float  pL[4][4 * 36];

    int wave = threadIdx.x >> 6;
    int lane = threadIdx.x & 63;
    // XCD swizzle: blocks of one n land on one XCD (round-robin assumption)
    int B    = blockIdx.x;                 // 8192 blocks
    int n    = (B & 7) * 16 + (B >> 9);    // 0..127
    int wing = (B >> 3) & 63;
    int win  = wing * 4 + wave;            // 0..255
    int row  = n * P2 + win;
    int b    = n >> 4, head = n & 15;

    float4* vs4 = vL[wave];
    float4* qs4 = qL[wave];
    float*  ps  = pL[wave];

    int l2 = lane & 31, half = lane >> 5;
    int kk = l2 >> 2, tt = l2 & 3;
    int mywin = idxin[row * KSEL + kk];

    // ---- q stage: 48 lanes, one float4 each (global b128 -> LDS b128) ----
    const float4* qp = (const float4*)(qw + ((size_t)n * P2 + win) * 192);
    if (lane < 48) {
        int r = lane / 12, c4 = lane % 12;
        qs4[r * 13 + c4] = qp[lane];
    }

    // ---- gather: lanes 0-31 key -> regs; lanes 32-63 value -> LDS ----
    const float4* src4 = (const float4*)
        ((half ? vw : kw) + (((size_t)n * P2 + mywin) * 4 + tt) * DH);
    float4 kreg[12];
    if (half) {
        #pragma unroll
        for (int c4 = 0; c4 < 12; c4++)
            vs4[l2 * 13 + c4] = src4[c4];
    } else {
        #pragma unroll
        for (int c4 = 0; c4 < 12; c4++)
            kreg[c4] = src4[c4];
    }
    __syncthreads();

    // ---- S = q @ K^T (lanes 0-31, one key each), softmax over 32 keys ----
    if (!half) {
        float s4[4];
        #pragma unroll
        for (int r = 0; r < 4; r++) {
            float acc = 0.f;
            #pragma unroll
            for (int c4 = 0; c4 < 12; c4++) {
                float4 q4 = qs4[r * 13 + c4];      // broadcast read
                acc = fmaf(q4.x, kreg[c4].x, acc);
                acc = fmaf(q4.y, kreg[c4].y, acc);
                acc = fmaf(q4.z, kreg[c4].z, acc);
                acc = fmaf(q4.w, kreg[c4].w, acc);
            }
            s4[r] = acc;
        }
        #pragma unroll
        for (int r = 0; r < 4; r++) {
            float m = s4[r];
            #pragma unroll
            for (int mm = 16; mm >= 1; mm >>= 1)
                m = fmaxf(m, __shfl_xor(m, mm, 64));
            float p = __expf(s4[r] - m);
            float sum = p;
            #pragma unroll
            for (int mm = 16; mm >= 1; mm >>= 1)
                sum += __shfl_xor(sum, mm, 64);
            ps[r * 36 + l2] = p / sum;
        }
    }
    __syncthreads();

    // ---- O = P @ V : 48 lanes, one float4 output each ----
    if (lane < 48) {
        int r = lane / 12, c4 = lane % 12;
        const float4* psv = (const float4*)(ps + r * 36);
        float4 acc = {0.f, 0.f, 0.f, 0.f};
        #pragma unroll
        for (int k2q = 0; k2q < 8; k2q++) {
            float4 p4 = psv[k2q];                  // broadcast read
            float4 v0 = vs4[(k2q * 4 + 0) * 13 + c4];
            float4 v1 = vs4[(k2q * 4 + 1) * 13 + c4];
            float4 v2 = vs4[(k2q * 4 + 2) * 13 + c4];
            float4 v3 = vs4[(k2q * 4 + 3) * 13 + c4];
            acc.x = fmaf(p4.x, v0.x, acc.x); acc.y = fmaf(p4.x, v0.y, acc.y);
            acc.z = fmaf(p4.x, v0.z, acc.z); acc.w = fmaf(p4.x, v0.w, acc.w);
            acc.x = fmaf(p4.y, v1.x, acc.x); acc.y = fmaf(p4.y, v1.y, acc.y);
            acc.z = fmaf(p4.y, v1.z, acc.z); acc.w = fmaf(p4.y, v1.w, acc.w);
            acc.x = fmaf(p4.z, v2.x, acc.x); acc.y = fmaf(p4.z, v2.y, acc.y);
            acc.z = fmaf(p4.z, v2.z, acc.z); acc.w = fmaf(p4.z, v2.w, acc.w);
            acc.x = fmaf(p4.w, v3.x, acc.x); acc.y = fmaf(p4.w, v3.y, acc.y);
            acc.z = fmaf(p4.w, v3.z, acc.z); acc.w = fmaf(p4.w, v3.w, acc.w);
        }
        int i0 = win >> 4, j0 = win & 15;
        int Aq = r >> 1, Bq = r & 1;
        int rowp = Bq * 16 + i0, colp = Aq * 16 + j0;
        float* op = out + ((size_t)b * 1024 + rowp * 32 + colp) * D
                        + head * DH + c4 * 4;
        *(float4*)op = acc;
    }
}

// ---------------------------------------------------------------------------
// Fallback A (ws just fits qkv): fused top-8 + attention (round-5 version).
// ---------------------------------------------------------------------------
__global__ __launch_bounds__(256) void topk_attn(
    const float* __restrict__ adjg,
    const float* __restrict__ qw,
    const float* __restrict__ kw,
    const float* __restrict__ vw,
    float* __restrict__ out)
{
    __shared__ float qL[4][192];
    __shared__ float vL[4][32 * VSTRIDE];
    __shared__ float pL[4][4 * PSTRIDE];

    int wave = threadIdx.x >> 6;
    int lane = threadIdx.x & 63;
    int unit = blockIdx.x * 4 + wave;
    int n    = unit >> 8;
    int win  = unit & 255;
    int b    = n >> 4, head = n & 15;

    float* qs = qL[wave];
    float* vs = vL[wave];
    float* ps = pL[wave];

    const float* arow = adjg + ((size_t)n * P2 + win) * P2;
    float4 av4 = *(const float4*)(arow + lane * 4);
    float vals[4] = {av4.x, av4.y, av4.z, av4.w};

    int l2 = lane & 31;
    int kk = l2 >> 2, tt = l2 & 3;
    int mywin = 0;
    #pragma unroll
    for (int it = 0; it < KSEL; it++) {
        float bv = vals[0]; int bidx = lane * 4;
        #pragma unroll
        for (int s = 1; s < 4; s++)
            if (vals[s] > bv) { bv = vals[s]; bidx = lane * 4 + s; }
        #pragma unroll
        for (int m = 32; m >= 1; m >>= 1) {
            float ov = __shfl_xor(bv, m, 64);
            int   oi = __shfl_xor(bidx, m, 64);
            if (ov > bv || (ov == bv && oi < bidx)) { bv = ov; bidx = oi; }
        }
        if (kk == it) mywin = bidx;
        #pragma unroll
        for (int s = 0; s < 4; s++)
            if (lane * 4 + s == bidx) vals[s] = -INFINITY;
    }

    const float* qp = qw + ((size_t)n * P2 + win) * 192;
    #pragma unroll
    for (int s = 0; s < 3; s++)
        qs[lane + 64 * s] = qp[lane + 64 * s];

    int half = lane >> 5;
    const float* src = (half ? vw : kw) + (((size_t)n * P2 + mywin) * 4 + tt) * DH;
    float kreg[48];
    if (half) {
        #pragma unroll
        for (int c4 = 0; c4 < 12; c4++) {
            float4 t = *(const float4*)(src + c4 * 4);
            float* dst = vs + l2 * VSTRIDE + c4 * 4;
            dst[0] = t.x; dst[1] = t.y; dst[2] = t.z; dst[3] = t.w;
        }
    } else {
        #pragma unroll
        for (int c4 = 0; c4 < 12; c4++) {
            float4 t = *(const float4*)(src + c4 * 4);
            kreg[c4*4 + 0] = t.x;
            kreg[c4*4 + 1] = t.y;
            kreg[c4*4 + 2] = t.z;
            kreg[c4*4 + 3] = t.w;
        }
    }
    __syncthreads();

    if (!half) {
        float s4[4] = {0.f, 0.f, 0.f, 0.f};
        #pragma unroll
        for (int c = 0; c < 48; c++) {
            float kc = kreg[c];
            s4[0] = fmaf(qs[c],       kc, s4[0]);
            s4[1] = fmaf(qs[48 + c],  kc, s4[1]);
            s4[2] = fmaf(qs[96 + c],  kc, s4[2]);
            s4[3] = fmaf(qs[144 + c], kc, s4[3]);
        }
        #pragma unroll
        for (int r = 0; r < 4; r++) {
            float m = s4[r];
            #pragma unroll
            for (int mm = 16; mm >= 1; mm >>= 1)
                m = fmaxf(m, __shfl_xor(m, mm, 64));
            float p = __expf(s4[r] - m);
            float sum = p;
            #pragma unroll
            for (int mm = 16; mm >= 1; mm >>= 1)
                sum += __shfl_xor(sum, mm, 64);
            ps[r * PSTRIDE + l2] = p / sum;
        }
    }
    __syncthreads();

    int i0 = win >> 4, j0 = win & 15;
    #pragma unroll
    for (int e = 0; e < 3; e++) {
        int idx = lane + 64 * e;
        int r = idx / 48, c = idx % 48;
        float acc = 0.f;
        #pragma unroll
        for (int k2 = 0; k2 < 32; k2++)
            acc = fmaf(ps[r * PSTRIDE + k2], vs[k2 * VSTRIDE + c], acc);
        int Aq = r >> 1, Bq = r & 1;
        int rowp = Bq * 16 + i0, colp = Aq * 16 + j0;
        out[((size_t)b * 1024 + rowp * 32 + colp) * D + head * DH + c] = acc;
    }
}

// ---------------------------------------------------------------------------
// Fallback B (zero workspace): fully fused, round-3 version.
// ---------------------------------------------------------------------------
__global__ __launch_bounds__(256) void fused_attn(
    const float* __restrict__ x,
    const float* __restrict__ adjg,
    const float* __restrict__ w,
    const float* __restrict__ gamma,
    const float* __restrict__ beta,
    const float* __restrict__ mean,
    const float* __restrict__ var,
    float* __restrict__ out)
{
    __shared__ float wL[3][25][48];
    __shared__ float bnI[3][48], bnS[3][48];
    __shared__ float qL[4][192];
    __shared__ float vL[4][32 * VSTRIDE];
    __shared__ float pL[4][4 * PSTRIDE];

    int tid  = threadIdx.x;
    int wave = tid >> 6, lane = tid & 63;
    int unit = blockIdx.x * 4 + wave;
    int n    = unit >> 8;
    int win  = unit & 255;
    int b    = n >> 4, head = n & 15;

    for (int j = tid; j < 3600; j += 256) {
        int chunk = j / 1200, rem = j % 1200, t = rem / 48, cc = rem % 48;
        wL[chunk][t][cc] = w[(size_t)chunk * D * 25 + (head * DH + cc) * 25 + t];
    }
    for (int j = tid; j < 144; j += 256) {
        int chunk = j / 48, cc = j % 48;
        int g = chunk * D + head * DH + cc;
        float inv = gamma[g] * rsqrtf(var[g] + 1e-5f);
        bnI[chunk][cc] = inv;
        bnS[chunk][cc] = beta[g] - mean[g] * inv;
    }
    __syncthreads();

    float* qs = qL[wave];
    float* vs = vL[wave];
    float* ps = pL[wave];

    const float* arow = adjg + ((size_t)n * P2 + win) * P2;
    float4 av4 = *(const float4*)(arow + lane * 4);
    float vals[4] = {av4.x, av4.y, av4.z, av4.w};

    int l2 = lane & 31;
    int kk = l2 >> 2, tt = l2 & 3;
    int mywin = 0;
    #pragma unroll
    for (int it = 0; it < KSEL; it++) {
        float bv = vals[0]; int bidx = lane * 4;
        #pragma unroll
        for (int s = 1; s < 4; s++)
            if (vals[s] > bv) { bv = vals[s]; bidx = lane * 4 + s; }
        #pragma unroll
        for (int m = 32; m >= 1; m >>= 1) {
            float ov = __shfl_xor(bv, m, 64);
            int   oi = __shfl_xor(bidx, m, 64);
            if (ov > bv || (ov == bv && oi < bidx)) { bv = ov; bidx = oi; }
        }
        if (kk == it) mywin = bidx;
        #pragma unroll
        for (int s = 0; s < 4; s++)
            if (lane * 4 + s == bidx) vals[s] = -INFINITY;
    }

    const float scale = 0.03608439182435161f;
    int i0 = win >> 4, j0 = win & 15;
    const float* xbh = x + (size_t)b * 1024 * D + head * DH;

    #pragma unroll
    for (int e = 0; e < 3; e++) {
        int idx = lane + 64 * e;
        int r = idx / 48, cc = idx % 48;
        int yq  = (r >> 1) * 16 + i0;
        int xq0 = (r & 1) * 16 + j0;
        float acc = 0.f;
        for (int ty = 0; ty < 5; ty++) {
            int yy = yq + ty - 2;
            if (yy < 0 || yy > 31) continue;
            for (int tx = 0; tx < 5; tx++) {
                int xx = xq0 + tx - 2;
                if (xx < 0 || xx > 31) continue;
                acc = fmaf(xbh[(size_t)(yy * 32 + xx) * D + cc],
                           wL[0][ty * 5 + tx][cc], acc);
            }
        }
        qs[idx] = (acc * bnI[0][cc] + bnS[0][cc]) * scale;
    }

    int half  = lane >> 5;
    int chunk = 1 + half;
    float accv[48];
    {
        int yk  = (tt >> 1) * 16 + (mywin >> 4);
        int xk0 = (tt & 1) * 16 + (mywin & 15);
        #pragma unroll
        for (int cc = 0; cc < 48; cc++) accv[cc] = 0.f;
        for (int ty = 0; ty < 5; ty++) {
            int yy = yk + ty - 2;
            if (yy < 0 || yy > 31) continue;
            for (int tx = 0; tx < 5; tx++) {
                int xx = xk0 + tx - 2;
                if (xx < 0 || xx > 31) continue;
                const float* px = xbh + (size_t)(yy * 32 + xx) * D;
                const float* wt = wL[chunk][ty * 5 + tx];
                #pragma unroll
                for (int c4 = 0; c4 < 12; c4++) {
                    float4 xv = *(const float4*)(px + c4 * 4);
                    accv[c4*4+0] = fmaf(xv.x, wt[c4*4+0], accv[c4*4+0]);
                    accv[c4*4+1] = fmaf(xv.y, wt[c4*4+1], accv[c4*4+1]);
                    accv[c4*4+2] = fmaf(xv.z, wt[c4*4+2], accv[c4*4+2]);
                    accv[c4*4+3] = fmaf(xv.w, wt[c4*4+3], accv[c4*4+3]);
                }
            }
        }
        #pragma unroll
        for (int cc = 0; cc < 48; cc++) {
            float val = accv[cc] * bnI[chunk][cc] + bnS[chunk][cc];
            if (half) vs[l2 * VSTRIDE + cc] = val;
            else      accv[cc] = val;
        }
    }
    __syncthreads();

    if (!half) {
        float s4[4] = {0.f, 0.f, 0.f, 0.f};
        #pragma unroll
        for (int c = 0; c < 48; c++) {
            float kc = accv[c];
            s4[0] = fmaf(qs[c],       kc, s4[0]);
            s4[1] = fmaf(qs[48 + c],  kc, s4[1]);
            s4[2] = fmaf(qs[96 + c],  kc, s4[2]);
            s4[3] = fmaf(qs[144 + c], kc, s4[3]);
        }
        #pragma unroll
        for (int r = 0; r < 4; r++) {
            float m = s4[r];
            #pragma unroll
            for (int mm = 16; mm >= 1; mm >>= 1)
                m = fmaxf(m, __shfl_xor(m, mm, 64));
            float p = __expf(s4[r] - m);
            float sum = p;
            #pragma unroll
            for (int mm = 16; mm >= 1; mm >>= 1)
                sum += __shfl_xor(sum, mm, 64);
            ps[r * PSTRIDE + l2] = p / sum;
        }
    }
    __syncthreads();

    #pragma unroll
    for (int e = 0; e < 3; e++) {
        int idx = lane + 64 * e;
        int r = idx / 48, c = idx % 48;
        float acc = 0.f;
        #pragma unroll
        for (int k2 = 0; k2 < 32; k2++)
            acc = fmaf(ps[r * PSTRIDE + k2], vs[k2 * VSTRIDE + c], acc);
        int Aq = r >> 1, Bq = r & 1;
        int rowp = Bq * 16 + i0, colp = Aq * 16 + j0;
        out[((size_t)b * 1024 + rowp * 32 + colp) * D + head * DH + c] = acc;
    }
}

extern "C" void kernel_launch(void* const* d_in, const int* in_sizes, int n_in,
                              void* d_out, int out_size, void* d_ws, size_t ws_size,
                              hipStream_t stream)
{
    const float* x     = (const float*)d_in[0];
    // d_in[1] = noise (unused by reference)
    const float* adjg  = (const float*)d_in[2];
    const float* w     = (const float*)d_in[3];
    const float* gamma = (const float*)d_in[4];
    const float* beta  = (const float*)d_in[5];
    const float* mean  = (const float*)d_in[6];
    const float* var   = (const float*)d_in[7];
    // d_in[8] = sparsity (=8, compile-time KSEL)

    const size_t NQKV   = (size_t)8 * HEADS * P2 * 4 * DH;   // 6291456 elements
    const size_t NROWS  = (size_t)8 * HEADS * P2;            // 32768
    const size_t need2  = 3 * NQKV * sizeof(float);
    const size_t need3  = need2 + NROWS * KSEL * sizeof(int);

    if (ws_size >= need3) {
        float* qw  = (float*)d_ws;
        float* kw  = qw + NQKV;
        float* vw  = kw + NQKV;
        int*   idx = (int*)(vw + NQKV);
        conv_qkv<<<768, 256, 0, stream>>>(x, w, gamma, beta, mean, var,
                                          qw, kw, vw);
        topk_idx_kernel<<<8192, 256, 0, stream>>>(adjg, idx);
        attn_kernel<<<8192, 256, 0, stream>>>(idx, qw, kw, vw, (float*)d_out);
    } else if (ws_size >= need2) {
        float* qw = (float*)d_ws;
        float* kw = qw + NQKV;
        float* vw = kw + NQKV;
        conv_qkv<<<768, 256, 0, stream>>>(x, w, gamma, beta, mean, var,
                                          qw, kw, vw);
        topk_attn<<<8192, 256, 0, stream>>>(adjg, qw, kw, vw, (float*)d_out);
    } else {
        fused_attn<<<8192, 256, 0, stream>>>(x, adjg, w, gamma, beta, mean, var,
                                             (float*)d_out);
    }
}

// Round 7
// 215.430 us; speedup vs baseline: 1.1418x; 1.0727x over previous
//
#include <hip/hip_runtime.h>
#include <hip/hip_bf16.h>
#include <math.h>

#define D 768
#define HEADS 16
#define DH 48
#define P2 256
#define KSEL 8

#define VSTRIDE 49   // (fallback kernel) pad 48 -> 49
#define PSTRIDE 33   // (fallback kernel) pad 32 -> 33

// ---------------------------------------------------------------------------
// Kernel 1 (fused prep): grid-partitioned conv+BN (blocks 0..767) and
// top-8 scan (blocks 768..8959). Conv is VALU-bound, topk is HBM-bound;
// running them in one dispatch overlaps the two pipes.
// ---------------------------------------------------------------------------
__global__ __launch_bounds__(256) void prep_kernel(
    const float* __restrict__ x,      // (8,1024,768) fp32
    const float* __restrict__ w,      // (3,768,1,5,5)
    const float* __restrict__ gamma,  // (3,768)
    const float* __restrict__ beta,
    const float* __restrict__ mean,
    const float* __restrict__ var,
    const float* __restrict__ adjg,   // (32768,256)
    float* __restrict__ qw, float* __restrict__ kw, float* __restrict__ vw,
    int* __restrict__ idxout)         // (32768,8)
{
    if (blockIdx.x >= 768) {
        // ---------------- top-8 part ----------------
        int wave = threadIdx.x >> 6;
        int lane = threadIdx.x & 63;
        int row  = (blockIdx.x - 768) * 4 + wave;   // 0..32767

        const float* arow = adjg + (size_t)row * P2;
        float4 av4 = *(const float4*)(arow + lane * 4);
        float vals[4] = {av4.x, av4.y, av4.z, av4.w};

        int myidx = 0;
        #pragma unroll
        for (int it = 0; it < KSEL; it++) {
            float bv = vals[0]; int bidx = lane * 4;
            #pragma unroll
            for (int s = 1; s < 4; s++)
                if (vals[s] > bv) { bv = vals[s]; bidx = lane * 4 + s; }
            #pragma unroll
            for (int m = 32; m >= 1; m >>= 1) {
                float ov = __shfl_xor(bv, m, 64);
                int   oi = __shfl_xor(bidx, m, 64);
                if (ov > bv || (ov == bv && oi < bidx)) { bv = ov; bidx = oi; }
            }
            if (lane == it) myidx = bidx;
            #pragma unroll
            for (int s = 0; s < 4; s++)
                if (lane * 4 + s == bidx) vals[s] = -INFINITY;
        }
        if (lane < KSEL)
            idxout[row * KSEL + lane] = myidx;
        return;
    }

    // ---------------- conv+BN part ----------------
    int bi   = blockIdx.x;            // 0..767
    int b    = bi / 96;
    int rem  = bi % 96;
    int y    = rem / 3;
    int chunk = rem % 3;
    int c = chunk * 256 + threadIdx.x;

    float wq[25], wk_[25], wv[25];
    const float* wp = w + (size_t)c * 25;
    #pragma unroll
    for (int i = 0; i < 25; i++) wq[i]  = wp[i];
    #pragma unroll
    for (int i = 0; i < 25; i++) wk_[i] = wp[D * 25 + i];
    #pragma unroll
    for (int i = 0; i < 25; i++) wv[i]  = wp[2 * D * 25 + i];

    float invq = gamma[c]       * rsqrtf(var[c]       + 1e-5f);
    float invk = gamma[D + c]   * rsqrtf(var[D + c]   + 1e-5f);
    float invv = gamma[2*D + c] * rsqrtf(var[2*D + c] + 1e-5f);
    float shq = beta[c]       - mean[c]       * invq;
    float shk = beta[D + c]   - mean[D + c]   * invk;
    float shv = beta[2*D + c] - mean[2*D + c] * invv;

    const float scale = 0.03608439182435161f;   // 768^-0.5 folded into q
    invq *= scale; shq *= scale;

    const float* xb = x + (size_t)b * 1024 * D + c;

    float a[5][5];
    bool yok[5];
    #pragma unroll
    for (int i = 0; i < 5; i++) {
        int yy = y - 2 + i;
        yok[i] = (yy >= 0 && yy < 32);
        a[i][0] = 0.f; a[i][1] = 0.f;
        a[i][2] = yok[i] ? xb[(yy * 32 + 0) * D] : 0.f;
        a[i][3] = yok[i] ? xb[(yy * 32 + 1) * D] : 0.f;
        a[i][4] = yok[i] ? xb[(yy * 32 + 2) * D] : 0.f;
    }

    int head = c / DH, cc = c % DH;
    int i0 = y & 15, A = y >> 4;
    int n = b * HEADS + head;

    for (int xx = 0; xx < 32; xx++) {
        float sq = 0.f, sk = 0.f, sv = 0.f;
        #pragma unroll
        for (int i = 0; i < 5; i++)
        #pragma unroll
        for (int j = 0; j < 5; j++) {
            float av = a[i][j];
            sq = fmaf(av, wq[i*5+j],  sq);
            sk = fmaf(av, wk_[i*5+j], sk);
            sv = fmaf(av, wv[i*5+j],  sv);
        }
        int j0 = xx & 15, Bq = xx >> 4;
        int win = i0 * 16 + j0, slot = A * 2 + Bq;
        size_t off = (((size_t)n * P2 + win) * 4 + slot) * DH + cc;
        qw[off] = sq * invq + shq;
        kw[off] = sk * invk + shk;
        vw[off] = sv * invv + shv;
        #pragma unroll
        for (int i = 0; i < 5; i++)
        #pragma unroll
        for (int j = 0; j < 4; j++)
            a[i][j] = a[i][j+1];
        int xn = xx + 3;
        bool xok = (xn < 32);
        #pragma unroll
        for (int i = 0; i < 5; i++) {
            int yy = y - 2 + i;
            a[i][4] = (yok[i] && xok) ? xb[(yy * 32 + xn) * D] : 0.f;
        }
    }
}

// ---------------------------------------------------------------------------
// Kernel 2: attention, all-64-lane balanced. One wave per (n,win);
// 4 waves/block sharing n; XCD-locality swizzle.
// Lane (l2,h): loads k-row[l2] half h into regs, v-row[l2] half h into LDS;
// computes 4 partial QK dots (24 elems), combines via shfl_xor(32);
// half h runs softmax for q-rows {2h, 2h+1}. PV: 48 lanes x float4.
// LDS/block 32256 B -> 5 blocks/CU.
// ---------------------------------------------------------------------------
__global__ __launch_bounds__(256) void attn_kernel(
    const int*   __restrict__ idxin,  // (32768, 8)
    const float* __restrict__ qw,     // pre-scaled
    const float* __restrict__ kw,
    const float* __restrict__ vw,
    float* __restrict__ out)          // (8,1024,768) fp32
{
    __shared__ float4 vL[4][32 * 13];
    __shared__ float4 qL[4][4 * 13];
    __shared__ float  pL[4][4 * 36];

    int wave = threadIdx.x >> 6;
    int lane = threadIdx.x & 63;
    int B    = blockIdx.x;                 // 8192 blocks
    int n    = (B & 7) * 16 + (B >> 9);    // 0..127 (XCD swizzle)
    int wing = (B >> 3) & 63;
    int win  = wing * 4 + wave;            // 0..255
    int row  = n * P2 + win;
    int b    = n >> 4, head = n & 15;

    float4* vs4 = vL[wave];
    float4* qs4 = qL[wave];
    float*  ps  = pL[wave];

    int l2 = lane & 31, half = lane >> 5;
    int kk = l2 >> 2, tt = l2 & 3;
    int mywin = idxin[row * KSEL + kk];    // issue idx load first

    // ---- q stage: 48 lanes, one float4 each ----
    const float4* qp = (const float4*)(qw + ((size_t)n * P2 + win) * 192);
    if (lane < 48) {
        int r = lane / 12, c4 = lane % 12;
        qs4[r * 13 + c4] = qp[lane];
    }

    // ---- gather: lane (l2,h) loads k half -> regs, v half -> LDS ----
    size_t gbase = (((size_t)n * P2 + mywin) * 4 + tt) * DH + half * 24;
    const float4* srcK = (const float4*)(kw + gbase);
    const float4* srcV = (const float4*)(vw + gbase);
    float4 kregh[6];
    #pragma unroll
    for (int j = 0; j < 6; j++) kregh[j] = srcK[j];
    #pragma unroll
    for (int j = 0; j < 6; j++) vs4[l2 * 13 + half * 6 + j] = srcV[j];
    __syncthreads();

    // ---- S partials: 4 q-rows x 24 elems, combine across halves ----
    float s4[4];
    #pragma unroll
    for (int r = 0; r < 4; r++) {
        float acc = 0.f;
        #pragma unroll
        for (int j = 0; j < 6; j++) {
            float4 q4 = qs4[r * 13 + half * 6 + j];  // broadcast read
            acc = fmaf(q4.x, kregh[j].x, acc);
            acc = fmaf(q4.y, kregh[j].y, acc);
            acc = fmaf(q4.z, kregh[j].z, acc);
            acc = fmaf(q4.w, kregh[j].w, acc);
        }
        s4[r] = acc;
    }
    #pragma unroll
    for (int r = 0; r < 4; r++)
        s4[r] += __shfl_xor(s4[r], 32, 64);          // full dot on all lanes

    // ---- softmax: half h handles q-rows 2h, 2h+1 (32 keys each) ----
    #pragma unroll
    for (int e = 0; e < 2; e++) {
        int r = 2 * half + e;
        float sv = s4[r];
        float m = sv;
        #pragma unroll
        for (int mm = 16; mm >= 1; mm >>= 1)
            m = fmaxf(m, __shfl_xor(m, mm, 64));     // stays within half
        float p = __expf(sv - m);
        float sum = p;
        #pragma unroll
        for (int mm = 16; mm >= 1; mm >>= 1)
            sum += __shfl_xor(sum, mm, 64);
        ps[r * 36 + l2] = p / sum;
    }
    __syncthreads();

    // ---- O = P @ V : 48 lanes, one float4 output each ----
    if (lane < 48) {
        int r = lane / 12, c4 = lane % 12;
        const float4* psv = (const float4*)(ps + r * 36);
        float4 acc = {0.f, 0.f, 0.f, 0.f};
        #pragma unroll
        for (int k2q = 0; k2q < 8; k2q++) {
            float4 p4 = psv[k2q];                    // broadcast read
            float4 v0 = vs4[(k2q * 4 + 0) * 13 + c4];
            float4 v1 = vs4[(k2q * 4 + 1) * 13 + c4];
            float4 v2 = vs4[(k2q * 4 + 2) * 13 + c4];
            float4 v3 = vs4[(k2q * 4 + 3) * 13 + c4];
            acc.x = fmaf(p4.x, v0.x, acc.x); acc.y = fmaf(p4.x, v0.y, acc.y);
            acc.z = fmaf(p4.x, v0.z, acc.z); acc.w = fmaf(p4.x, v0.w, acc.w);
            acc.x = fmaf(p4.y, v1.x, acc.x); acc.y = fmaf(p4.y, v1.y, acc.y);
            acc.z = fmaf(p4.y, v1.z, acc.z); acc.w = fmaf(p4.y, v1.w, acc.w);
            acc.x = fmaf(p4.z, v2.x, acc.x); acc.y = fmaf(p4.z, v2.y, acc.y);
            acc.z = fmaf(p4.z, v2.z, acc.z); acc.w = fmaf(p4.z, v2.w, acc.w);
            acc.x = fmaf(p4.w, v3.x, acc.x); acc.y = fmaf(p4.w, v3.y, acc.y);
            acc.z = fmaf(p4.w, v3.z, acc.z); acc.w = fmaf(p4.w, v3.w, acc.w);
        }
        int i0 = win >> 4, j0 = win & 15;
        int Aq = r >> 1, Bq = r & 1;
        int rowp = Bq * 16 + i0, colp = Aq * 16 + j0;
        float* op = out + ((size_t)b * 1024 + rowp * 32 + colp) * D
                        + head * DH + c4 * 4;
        *(float4*)op = acc;
    }
}

// ---------------------------------------------------------------------------
// Fallback (zero workspace): fully fused, round-3 version.
// ---------------------------------------------------------------------------
__global__ __launch_bounds__(256) void fused_attn(
    const float* __restrict__ x,
    const float* __restrict__ adjg,
    const float* __restrict__ w,
    const float* __restrict__ gamma,
    const float* __restrict__ beta,
    const float* __restrict__ mean,
    const float* __restrict__ var,
    float* __restrict__ out)
{
    __shared__ float wL[3][25][48];
    __shared__ float bnI[3][48], bnS[3][48];
    __shared__ float qL[4][192];
    __shared__ float vL[4][32 * VSTRIDE];
    __shared__ float pL[4][4 * PSTRIDE];

    int tid  = threadIdx.x;
    int wave = tid >> 6, lane = tid & 63;
    int unit = blockIdx.x * 4 + wave;
    int n    = unit >> 8;
    int win  = unit & 255;
    int b    = n >> 4, head = n & 15;

    for (int j = tid; j < 3600; j += 256) {
        int chunk = j / 1200, rem = j % 1200, t = rem / 48, cc = rem % 48;
        wL[chunk][t][cc] = w[(size_t)chunk * D * 25 + (head * DH + cc) * 25 + t];
    }
    for (int j = tid; j < 144; j += 256) {
        int chunk = j / 48, cc = j % 48;
        int g = chunk * D + head * DH + cc;
        float inv = gamma[g] * rsqrtf(var[g] + 1e-5f);
        bnI[chunk][cc] = inv;
        bnS[chunk][cc] = beta[g] - mean[g] * inv;
    }
    __syncthreads();

    float* qs = qL[wave];
    float* vs = vL[wave];
    float* ps = pL[wave];

    const float* arow = adjg + ((size_t)n * P2 + win) * P2;
    float4 av4 = *(const float4*)(arow + lane * 4);
    float vals[4] = {av4.x, av4.y, av4.z, av4.w};

    int l2 = lane & 31;
    int kk = l2 >> 2, tt = l2 & 3;
    int mywin = 0;
    #pragma unroll
    for (int it = 0; it < KSEL; it++) {
        float bv = vals[0]; int bidx = lane * 4;
        #pragma unroll
        for (int s = 1; s < 4; s++)
            if (vals[s] > bv) { bv = vals[s]; bidx = lane * 4 + s; }
        #pragma unroll
        for (int m = 32; m >= 1; m >>= 1) {
            float ov = __shfl_xor(bv, m, 64);
            int   oi = __shfl_xor(bidx, m, 64);
            if (ov > bv || (ov == bv && oi < bidx)) { bv = ov; bidx = oi; }
        }
        if (kk == it) mywin = bidx;
        #pragma unroll
        for (int s = 0; s < 4; s++)
            if (lane * 4 + s == bidx) vals[s] = -INFINITY;
    }

    const float scale = 0.03608439182435161f;
    int i0 = win >> 4, j0 = win & 15;
    const float* xbh = x + (size_t)b * 1024 * D + head * DH;

    #pragma unroll
    for (int e = 0; e < 3; e++) {
        int idx = lane + 64 * e;
        int r = idx / 48, cc = idx % 48;
        int yq  = (r >> 1) * 16 + i0;
        int xq0 = (r & 1) * 16 + j0;
        float acc = 0.f;
        for (int ty = 0; ty < 5; ty++) {
            int yy = yq + ty - 2;
            if (yy < 0 || yy > 31) continue;
            for (int tx = 0; tx < 5; tx++) {
                int xx = xq0 + tx - 2;
                if (xx < 0 || xx > 31) continue;
                acc = fmaf(xbh[(size_t)(yy * 32 + xx) * D + cc],
                           wL[0][ty * 5 + tx][cc], acc);
            }
        }
        qs[idx] = (acc * bnI[0][cc] + bnS[0][cc]) * scale;
    }

    int half  = lane >> 5;
    int chunk = 1 + half;
    float accv[48];
    {
        int yk  = (tt >> 1) * 16 + (mywin >> 4);
        int xk0 = (tt & 1) * 16 + (mywin & 15);
        #pragma unroll
        for (int cc = 0; cc < 48; cc++) accv[cc] = 0.f;
        for (int ty = 0; ty < 5; ty++) {
            int yy = yk + ty - 2;
            if (yy < 0 || yy > 31) continue;
            for (int tx = 0; tx < 5; tx++) {
                int xx = xk0 + tx - 2;
                if (xx < 0 || xx > 31) continue;
                const float* px = xbh + (size_t)(yy * 32 + xx) * D;
                const float* wt = wL[chunk][ty * 5 + tx];
                #pragma unroll
                for (int c4 = 0; c4 < 12; c4++) {
                    float4 xv = *(const float4*)(px + c4 * 4);
                    accv[c4*4+0] = fmaf(xv.x, wt[c4*4+0], accv[c4*4+0]);
                    accv[c4*4+1] = fmaf(xv.y, wt[c4*4+1], accv[c4*4+1]);
                    accv[c4*4+2] = fmaf(xv.z, wt[c4*4+2], accv[c4*4+2]);
                    accv[c4*4+3] = fmaf(xv.w, wt[c4*4+3], accv[c4*4+3]);
                }
            }
        }
        #pragma unroll
        for (int cc = 0; cc < 48; cc++) {
            float val = accv[cc] * bnI[chunk][cc] + bnS[chunk][cc];
            if (half) vs[l2 * VSTRIDE + cc] = val;
            else      accv[cc] = val;
        }
    }
    __syncthreads();

    if (!half) {
        float s4[4] = {0.f, 0.f, 0.f, 0.f};
        #pragma unroll
        for (int c = 0; c < 48; c++) {
            float kc = accv[c];
            s4[0] = fmaf(qs[c],       kc, s4[0]);
            s4[1] = fmaf(qs[48 + c],  kc, s4[1]);
            s4[2] = fmaf(qs[96 + c],  kc, s4[2]);
            s4[3] = fmaf(qs[144 + c], kc, s4[3]);
        }
        #pragma unroll
        for (int r = 0; r < 4; r++) {
            float m = s4[r];
            #pragma unroll
            for (int mm = 16; mm >= 1; mm >>= 1)
                m = fmaxf(m, __shfl_xor(m, mm, 64));
            float p = __expf(s4[r] - m);
            float sum = p;
            #pragma unroll
            for (int mm = 16; mm >= 1; mm >>= 1)
                sum += __shfl_xor(sum, mm, 64);
            ps[r * PSTRIDE + l2] = p / sum;
        }
    }
    __syncthreads();

    #pragma unroll
    for (int e = 0; e < 3; e++) {
        int idx = lane + 64 * e;
        int r = idx / 48, c = idx % 48;
        float acc = 0.f;
        #pragma unroll
        for (int k2 = 0; k2 < 32; k2++)
            acc = fmaf(ps[r * PSTRIDE + k2], vs[k2 * VSTRIDE + c], acc);
        int Aq = r >> 1, Bq = r & 1;
        int rowp = Bq * 16 + i0, colp = Aq * 16 + j0;
        out[((size_t)b * 1024 + rowp * 32 + colp) * D + head * DH + c] = acc;
    }
}

extern "C" void kernel_launch(void* const* d_in, const int* in_sizes, int n_in,
                              void* d_out, int out_size, void* d_ws, size_t ws_size,
                              hipStream_t stream)
{
    const float* x     = (const float*)d_in[0];
    // d_in[1] = noise (unused by reference)
    const float* adjg  = (const float*)d_in[2];
    const float* w     = (const float*)d_in[3];
    const float* gamma = (const float*)d_in[4];
    const float* beta  = (const float*)d_in[5];
    const float* mean  = (const float*)d_in[6];
    const float* var   = (const float*)d_in[7];
    // d_in[8] = sparsity (=8, compile-time KSEL)

    const size_t NQKV   = (size_t)8 * HEADS * P2 * 4 * DH;   // 6291456 elements
    const size_t NROWS  = (size_t)8 * HEADS * P2;            // 32768
    const size_t need3  = 3 * NQKV * sizeof(float) + NROWS * KSEL * sizeof(int);

    if (ws_size >= need3) {
        float* qw  = (float*)d_ws;
        float* kw  = qw + NQKV;
        float* vw  = kw + NQKV;
        int*   idx = (int*)(vw + NQKV);
        prep_kernel<<<8960, 256, 0, stream>>>(x, w, gamma, beta, mean, var,
                                              adjg, qw, kw, vw, idx);
        attn_kernel<<<8192, 256, 0, stream>>>(idx, qw, kw, vw, (float*)d_out);
    } else {
        fused_attn<<<8192, 256, 0, stream>>>(x, adjg, w, gamma, beta, mean, var,
                                             (float*)d_out);
    }
}

// Round 8
// 209.874 us; speedup vs baseline: 1.1720x; 1.0265x over previous
//
#include <hip/hip_runtime.h>
#include <hip/hip_bf16.h>
#include <math.h>

#define D 768
#define HEADS 16
#define DH 48
#define P2 256
#define KSEL 8

#define VSTRIDE 49   // (fallback kernel) pad 48 -> 49
#define PSTRIDE 33   // (fallback kernel) pad 32 -> 33

#define CONV_BLOCKS 4608   // 8 b * 32 y * 3 chunk * 2 xc * 3 which
#define TOPK_BLOCKS 8192

// ---------------------------------------------------------------------------
// Kernel 1 (fused prep):
//  blocks [0, 4608): depthwise 5x5 conv + BN, ONE of {q,k,v} per block,
//    16 output columns per block, 256 channels (one chunk). 25 weights +
//    25-tap window fit in ~60 VGPRs -> no re-load, 18 blocks/CU.
//  blocks [4608, 12800): top-8 scan, value-only shuffle reduce + ballot.
// ---------------------------------------------------------------------------
__global__ __launch_bounds__(256) void prep_kernel(
    const float* __restrict__ x,      // (8,1024,768) fp32
    const float* __restrict__ w,      // (3,768,1,5,5)
    const float* __restrict__ gamma,  // (3,768)
    const float* __restrict__ beta,
    const float* __restrict__ mean,
    const float* __restrict__ var,
    const float* __restrict__ adjg,   // (32768,256)
    float* __restrict__ qw, float* __restrict__ kw, float* __restrict__ vw,
    int* __restrict__ idxout)         // (32768,8)
{
    if (blockIdx.x >= CONV_BLOCKS) {
        // ---------------- top-8 part ----------------
        int wave = threadIdx.x >> 6;
        int lane = threadIdx.x & 63;
        int row  = (blockIdx.x - CONV_BLOCKS) * 4 + wave;   // 0..32767

        const float* arow = adjg + (size_t)row * P2;
        float4 av4 = *(const float4*)(arow + lane * 4);
        float vals[4] = {av4.x, av4.y, av4.z, av4.w};

        int myidx = 0;
        #pragma unroll
        for (int it = 0; it < KSEL; it++) {
            // local argmax (strict > keeps lowest slot on exact ties)
            float bv = vals[0]; int bs = 0;
            if (vals[1] > bv) { bv = vals[1]; bs = 1; }
            if (vals[2] > bv) { bv = vals[2]; bs = 2; }
            if (vals[3] > bv) { bv = vals[3]; bs = 3; }
            // value-only max reduction across 64 lanes
            float gv = bv;
            #pragma unroll
            for (int m = 32; m >= 1; m >>= 1)
                gv = fmaxf(gv, __shfl_xor(gv, m, 64));
            // winner = lowest lane whose local max equals the global max
            unsigned long long mask = __ballot(bv == gv);
            int wlane = (int)__builtin_ctzll(mask);
            int wslot = __shfl(bs, wlane, 64);
            if (lane == it) myidx = wlane * 4 + wslot;
            if (lane == wlane) vals[wslot] = -INFINITY;
        }
        if (lane < KSEL)
            idxout[row * KSEL + lane] = myidx;
        return;
    }

    // ---------------- conv+BN part (one of q/k/v) ----------------
    int bi    = blockIdx.x;              // 0..4607
    int which = bi / 1536;               // 0=q 1=k 2=v
    int rem   = bi % 1536;
    int b     = rem / 192;
    int rem2  = rem % 192;
    int y     = rem2 / 6;
    int sub   = rem2 % 6;
    int chunk = sub >> 1;
    int xc    = sub & 1;
    int x0    = xc * 16;
    int c     = chunk * 256 + threadIdx.x;

    float wl[25];
    const float* wp = w + ((size_t)which * D + c) * 25;
    #pragma unroll
    for (int i = 0; i < 25; i++) wl[i] = wp[i];

    int g = which * D + c;
    float inv = gamma[g] * rsqrtf(var[g] + 1e-5f);
    float sh  = beta[g] - mean[g] * inv;
    if (which == 0) {
        const float scale = 0.03608439182435161f;   // 768^-0.5 folded into q
        inv *= scale; sh *= scale;
    }
    float* dst = (which == 0) ? qw : (which == 1) ? kw : vw;

    const float* xb = x + (size_t)b * 1024 * D + c;

    float a[5][5];
    bool yok[5];
    #pragma unroll
    for (int i = 0; i < 5; i++) {
        int yy = y - 2 + i;
        yok[i] = (yy >= 0 && yy < 32);
        #pragma unroll
        for (int j = 0; j < 5; j++) {
            int xxc = x0 - 2 + j;
            a[i][j] = (yok[i] && xxc >= 0 && xxc < 32)
                      ? xb[(yy * 32 + xxc) * D] : 0.f;
        }
    }

    int head = c / DH, cc = c % DH;
    int i0 = y & 15, A = y >> 4;
    int n = b * HEADS + head;

    for (int xx = x0; xx < x0 + 16; xx++) {
        float s = 0.f;
        #pragma unroll
        for (int i = 0; i < 5; i++)
        #pragma unroll
        for (int j = 0; j < 5; j++)
            s = fmaf(a[i][j], wl[i*5+j], s);
        int j0 = xx & 15, Bq = xx >> 4;
        int win = i0 * 16 + j0, slot = A * 2 + Bq;
        size_t off = (((size_t)n * P2 + win) * 4 + slot) * DH + cc;
        dst[off] = s * inv + sh;
        #pragma unroll
        for (int i = 0; i < 5; i++)
        #pragma unroll
        for (int j = 0; j < 4; j++)
            a[i][j] = a[i][j+1];
        int xn = xx + 3;
        bool xok = (xn < 32);
        #pragma unroll
        for (int i = 0; i < 5; i++) {
            int yy = y - 2 + i;
            a[i][4] = (yok[i] && xok) ? xb[(yy * 32 + xn) * D] : 0.f;
        }
    }
}

// ---------------------------------------------------------------------------
// Kernel 2: attention, all-64-lane balanced (unchanged from round 7).
// ---------------------------------------------------------------------------
__global__ __launch_bounds__(256) void attn_kernel(
    const int*   __restrict__ idxin,  // (32768, 8)
    const float* __restrict__ qw,     // pre-scaled
    const float* __restrict__ kw,
    const float* __restrict__ vw,
    float* __restrict__ out)          // (8,1024,768) fp32
{
    __shared__ float4 vL[4][32 * 13];
    __shared__ float4 qL[4][4 * 13];
    __shared__ float  pL[4][4 * 36];

    int wave = threadIdx.x >> 6;
    int lane = threadIdx.x & 63;
    int B    = blockIdx.x;                 // 8192 blocks
    int n    = (B & 7) * 16 + (B >> 9);    // 0..127 (XCD swizzle)
    int wing = (B >> 3) & 63;
    int win  = wing * 4 + wave;            // 0..255
    int row  = n * P2 + win;
    int b    = n >> 4, head = n & 15;

    float4* vs4 = vL[wave];
    float4* qs4 = qL[wave];
    float*  ps  = pL[wave];

    int l2 = lane & 31, half = lane >> 5;
    int kk = l2 >> 2, tt = l2 & 3;
    int mywin = idxin[row * KSEL + kk];

    const float4* qp = (const float4*)(qw + ((size_t)n * P2 + win) * 192);
    if (lane < 48) {
        int r = lane / 12, c4 = lane % 12;
        qs4[r * 13 + c4] = qp[lane];
    }

    size_t gbase = (((size_t)n * P2 + mywin) * 4 + tt) * DH + half * 24;
    const float4* srcK = (const float4*)(kw + gbase);
    const float4* srcV = (const float4*)(vw + gbase);
    float4 kregh[6];
    #pragma unroll
    for (int j = 0; j < 6; j++) kregh[j] = srcK[j];
    #pragma unroll
    for (int j = 0; j < 6; j++) vs4[l2 * 13 + half * 6 + j] = srcV[j];
    __syncthreads();

    float s4[4];
    #pragma unroll
    for (int r = 0; r < 4; r++) {
        float acc = 0.f;
        #pragma unroll
        for (int j = 0; j < 6; j++) {
            float4 q4 = qs4[r * 13 + half * 6 + j];
            acc = fmaf(q4.x, kregh[j].x, acc);
            acc = fmaf(q4.y, kregh[j].y, acc);
            acc = fmaf(q4.z, kregh[j].z, acc);
            acc = fmaf(q4.w, kregh[j].w, acc);
        }
        s4[r] = acc;
    }
    #pragma unroll
    for (int r = 0; r < 4; r++)
        s4[r] += __shfl_xor(s4[r], 32, 64);

    #pragma unroll
    for (int e = 0; e < 2; e++) {
        int r = 2 * half + e;
        float sv = s4[r];
        float m = sv;
        #pragma unroll
        for (int mm = 16; mm >= 1; mm >>= 1)
            m = fmaxf(m, __shfl_xor(m, mm, 64));
        float p = __expf(sv - m);
        float sum = p;
        #pragma unroll
        for (int mm = 16; mm >= 1; mm >>= 1)
            sum += __shfl_xor(sum, mm, 64);
        ps[r * 36 + l2] = p / sum;
    }
    __syncthreads();

    if (lane < 48) {
        int r = lane / 12, c4 = lane % 12;
        const float4* psv = (const float4*)(ps + r * 36);
        float4 acc = {0.f, 0.f, 0.f, 0.f};
        #pragma unroll
        for (int k2q = 0; k2q < 8; k2q++) {
            float4 p4 = psv[k2q];
            float4 v0 = vs4[(k2q * 4 + 0) * 13 + c4];
            float4 v1 = vs4[(k2q * 4 + 1) * 13 + c4];
            float4 v2 = vs4[(k2q * 4 + 2) * 13 + c4];
            float4 v3 = vs4[(k2q * 4 + 3) * 13 + c4];
            acc.x = fmaf(p4.x, v0.x, acc.x); acc.y = fmaf(p4.x, v0.y, acc.y);
            acc.z = fmaf(p4.x, v0.z, acc.z); acc.w = fmaf(p4.x, v0.w, acc.w);
            acc.x = fmaf(p4.y, v1.x, acc.x); acc.y = fmaf(p4.y, v1.y, acc.y);
            acc.z = fmaf(p4.y, v1.z, acc.z); acc.w = fmaf(p4.y, v1.w, acc.w);
            acc.x = fmaf(p4.z, v2.x, acc.x); acc.y = fmaf(p4.z, v2.y, acc.y);
            acc.z = fmaf(p4.z, v2.z, acc.z); acc.w = fmaf(p4.z, v2.w, acc.w);
            acc.x = fmaf(p4.w, v3.x, acc.x); acc.y = fmaf(p4.w, v3.y, acc.y);
            acc.z = fmaf(p4.w, v3.z, acc.z); acc.w = fmaf(p4.w, v3.w, acc.w);
        }
        int i0 = win >> 4, j0 = win & 15;
        int Aq = r >> 1, Bq = r & 1;
        int rowp = Bq * 16 + i0, colp = Aq * 16 + j0;
        float* op = out + ((size_t)b * 1024 + rowp * 32 + colp) * D
                        + head * DH + c4 * 4;
        *(float4*)op = acc;
    }
}

// ---------------------------------------------------------------------------
// Fallback (zero workspace): fully fused, round-3 version.
// ---------------------------------------------------------------------------
__global__ __launch_bounds__(256) void fused_attn(
    const float* __restrict__ x,
    const float* __restrict__ adjg,
    const float* __restrict__ w,
    const float* __restrict__ gamma,
    const float* __restrict__ beta,
    const float* __restrict__ mean,
    const float* __restrict__ var,
    float* __restrict__ out)
{
    __shared__ float wL[3][25][48];
    __shared__ float bnI[3][48], bnS[3][48];
    __shared__ float qL[4][192];
    __shared__ float vL[4][32 * VSTRIDE];
    __shared__ float pL[4][4 * PSTRIDE];

    int tid  = threadIdx.x;
    int wave = tid >> 6, lane = tid & 63;
    int unit = blockIdx.x * 4 + wave;
    int n    = unit >> 8;
    int win  = unit & 255;
    int b    = n >> 4, head = n & 15;

    for (int j = tid; j < 3600; j += 256) {
        int chunk = j / 1200, rem = j % 1200, t = rem / 48, cc = rem % 48;
        wL[chunk][t][cc] = w[(size_t)chunk * D * 25 + (head * DH + cc) * 25 + t];
    }
    for (int j = tid; j < 144; j += 256) {
        int chunk = j / 48, cc = j % 48;
        int g = chunk * D + head * DH + cc;
        float inv = gamma[g] * rsqrtf(var[g] + 1e-5f);
        bnI[chunk][cc] = inv;
        bnS[chunk][cc] = beta[g] - mean[g] * inv;
    }
    __syncthreads();

    float* qs = qL[wave];
    float* vs = vL[wave];
    float* ps = pL[wave];

    const float* arow = adjg + ((size_t)n * P2 + win) * P2;
    float4 av4 = *(const float4*)(arow + lane * 4);
    float vals[4] = {av4.x, av4.y, av4.z, av4.w};

    int l2 = lane & 31;
    int kk = l2 >> 2, tt = l2 & 3;
    int mywin = 0;
    #pragma unroll
    for (int it = 0; it < KSEL; it++) {
        float bv = vals[0]; int bidx = lane * 4;
        #pragma unroll
        for (int s = 1; s < 4; s++)
            if (vals[s] > bv) { bv = vals[s]; bidx = lane * 4 + s; }
        #pragma unroll
        for (int m = 32; m >= 1; m >>= 1) {
            float ov = __shfl_xor(bv, m, 64);
            int   oi = __shfl_xor(bidx, m, 64);
            if (ov > bv || (ov == bv && oi < bidx)) { bv = ov; bidx = oi; }
        }
        if (kk == it) mywin = bidx;
        #pragma unroll
        for (int s = 0; s < 4; s++)
            if (lane * 4 + s == bidx) vals[s] = -INFINITY;
    }

    const float scale = 0.03608439182435161f;
    int i0 = win >> 4, j0 = win & 15;
    const float* xbh = x + (size_t)b * 1024 * D + head * DH;

    #pragma unroll
    for (int e = 0; e < 3; e++) {
        int idx = lane + 64 * e;
        int r = idx / 48, cc = idx % 48;
        int yq  = (r >> 1) * 16 + i0;
        int xq0 = (r & 1) * 16 + j0;
        float acc = 0.f;
        for (int ty = 0; ty < 5; ty++) {
            int yy = yq + ty - 2;
            if (yy < 0 || yy > 31) continue;
            for (int tx = 0; tx < 5; tx++) {
                int xx = xq0 + tx - 2;
                if (xx < 0 || xx > 31) continue;
                acc = fmaf(xbh[(size_t)(yy * 32 + xx) * D + cc],
                           wL[0][ty * 5 + tx][cc], acc);
            }
        }
        qs[idx] = (acc * bnI[0][cc] + bnS[0][cc]) * scale;
    }

    int half  = lane >> 5;
    int chunk = 1 + half;
    float accv[48];
    {
        int yk  = (tt >> 1) * 16 + (mywin >> 4);
        int xk0 = (tt & 1) * 16 + (mywin & 15);
        #pragma unroll
        for (int cc = 0; cc < 48; cc++) accv[cc] = 0.f;
        for (int ty = 0; ty < 5; ty++) {
            int yy = yk + ty - 2;
            if (yy < 0 || yy > 31) continue;
            for (int tx = 0; tx < 5; tx++) {
                int xx = xk0 + tx - 2;
                if (xx < 0 || xx > 31) continue;
                const float* px = xbh + (size_t)(yy * 32 + xx) * D;
                const float* wt = wL[chunk][ty * 5 + tx];
                #pragma unroll
                for (int c4 = 0; c4 < 12; c4++) {
                    float4 xv = *(const float4*)(px + c4 * 4);
                    accv[c4*4+0] = fmaf(xv.x, wt[c4*4+0], accv[c4*4+0]);
                    accv[c4*4+1] = fmaf(xv.y, wt[c4*4+1], accv[c4*4+1]);
                    accv[c4*4+2] = fmaf(xv.z, wt[c4*4+2], accv[c4*4+2]);
                    accv[c4*4+3] = fmaf(xv.w, wt[c4*4+3], accv[c4*4+3]);
                }
            }
        }
        #pragma unroll
        for (int cc = 0; cc < 48; cc++) {
            float val = accv[cc] * bnI[chunk][cc] + bnS[chunk][cc];
            if (half) vs[l2 * VSTRIDE + cc] = val;
            else      accv[cc] = val;
        }
    }
    __syncthreads();

    if (!half) {
        float s4[4] = {0.f, 0.f, 0.f, 0.f};
        #pragma unroll
        for (int c = 0; c < 48; c++) {
            float kc = accv[c];
            s4[0] = fmaf(qs[c],       kc, s4[0]);
            s4[1] = fmaf(qs[48 + c],  kc, s4[1]);
            s4[2] = fmaf(qs[96 + c],  kc, s4[2]);
            s4[3] = fmaf(qs[144 + c], kc, s4[3]);
        }
        #pragma unroll
        for (int r = 0; r < 4; r++) {
            float m = s4[r];
            #pragma unroll
            for (int mm = 16; mm >= 1; mm >>= 1)
                m = fmaxf(m, __shfl_xor(m, mm, 64));
            float p = __expf(s4[r] - m);
            float sum = p;
            #pragma unroll
            for (int mm = 16; mm >= 1; mm >>= 1)
                sum += __shfl_xor(sum, mm, 64);
            ps[r * PSTRIDE + l2] = p / sum;
        }
    }
    __syncthreads();

    #pragma unroll
    for (int e = 0; e < 3; e++) {
        int idx = lane + 64 * e;
        int r = idx / 48, c = idx % 48;
        float acc = 0.f;
        #pragma unroll
        for (int k2 = 0; k2 < 32; k2++)
            acc = fmaf(ps[r * PSTRIDE + k2], vs[k2 * VSTRIDE + c], acc);
        int Aq = r >> 1, Bq = r & 1;
        int rowp = Bq * 16 + i0, colp = Aq * 16 + j0;
        out[((size_t)b * 1024 + rowp * 32 + colp) * D + head * DH + c] = acc;
    }
}

extern "C" void kernel_launch(void* const* d_in, const int* in_sizes, int n_in,
                              void* d_out, int out_size, void* d_ws, size_t ws_size,
                              hipStream_t stream)
{
    const float* x     = (const float*)d_in[0];
    // d_in[1] = noise (unused by reference)
    const float* adjg  = (const float*)d_in[2];
    const float* w     = (const float*)d_in[3];
    const float* gamma = (const float*)d_in[4];
    const float* beta  = (const float*)d_in[5];
    const float* mean  = (const float*)d_in[6];
    const float* var   = (const float*)d_in[7];
    // d_in[8] = sparsity (=8, compile-time KSEL)

    const size_t NQKV   = (size_t)8 * HEADS * P2 * 4 * DH;   // 6291456 elements
    const size_t NROWS  = (size_t)8 * HEADS * P2;            // 32768
    const size_t need3  = 3 * NQKV * sizeof(float) + NROWS * KSEL * sizeof(int);

    if (ws_size >= need3) {
        float* qw  = (float*)d_ws;
        float* kw  = qw + NQKV;
        float* vw  = kw + NQKV;
        int*   idx = (int*)(vw + NQKV);
        prep_kernel<<<CONV_BLOCKS + TOPK_BLOCKS, 256, 0, stream>>>(
            x, w, gamma, beta, mean, var, adjg, qw, kw, vw, idx);
        attn_kernel<<<8192, 256, 0, stream>>>(idx, qw, kw, vw, (float*)d_out);
    } else {
        fused_attn<<<8192, 256, 0, stream>>>(x, adjg, w, gamma, beta, mean, var,
                                             (float*)d_out);
    }
}

// Round 9
// 207.961 us; speedup vs baseline: 1.1828x; 1.0092x over previous
//
#include <hip/hip_runtime.h>
#include <hip/hip_bf16.h>
#include <math.h>

#define D 768
#define HEADS 16
#define DH 48
#define P2 256
#define KSEL 8

#define VSTRIDE 49   // (fallback kernel) pad 48 -> 49
#define PSTRIDE 33   // (fallback kernel) pad 32 -> 33

#define CONV_BLOCKS 4608   // 3 which * 8 b * 32 y * 3 chunk * 2 xc
#define TOPK_BLOCKS 4096   // 32768 rows / (4 waves * 2 rows)

// ---------------------------------------------------------------------------
// Kernel 1 (fused prep):
//  blocks [0, 4608): depthwise 5x5 conv + BN, ONE of {q,k,v}, 16 output
//    columns, 256 channels per block. xx-loop FULLY UNROLLED -> register
//    renaming removes all 20 window-shift movs per pixel.
//  blocks [4608, 8704): top-8 scan, 2 rows per wave (2x memory-level
//    parallelism + interleaved independent reduce chains).
// ---------------------------------------------------------------------------
__global__ __launch_bounds__(256) void prep_kernel(
    const float* __restrict__ x,      // (8,1024,768) fp32
    const float* __restrict__ w,      // (3,768,1,5,5)
    const float* __restrict__ gamma,  // (3,768)
    const float* __restrict__ beta,
    const float* __restrict__ mean,
    const float* __restrict__ var,
    const float* __restrict__ adjg,   // (32768,256)
    float* __restrict__ qw, float* __restrict__ kw, float* __restrict__ vw,
    int* __restrict__ idxout)         // (32768,8)
{
    if (blockIdx.x >= CONV_BLOCKS) {
        // ---------------- top-8 part: 2 rows per wave ----------------
        int wave = threadIdx.x >> 6;
        int lane = threadIdx.x & 63;
        int row0 = ((blockIdx.x - CONV_BLOCKS) * 4 + wave) * 2;  // 0..32766

        const float* ar0 = adjg + (size_t)row0 * P2;
        const float* ar1 = ar0 + P2;
        float4 a0 = *(const float4*)(ar0 + lane * 4);
        float4 a1 = *(const float4*)(ar1 + lane * 4);
        float v0[4] = {a0.x, a0.y, a0.z, a0.w};
        float v1[4] = {a1.x, a1.y, a1.z, a1.w};

        int myidx0 = 0, myidx1 = 0;
        #pragma unroll
        for (int it = 0; it < KSEL; it++) {
            // local argmax for both rows (strict > keeps lowest slot on ties)
            float b0 = v0[0]; int s0 = 0;
            float b1 = v1[0]; int s1 = 0;
            if (v0[1] > b0) { b0 = v0[1]; s0 = 1; }
            if (v1[1] > b1) { b1 = v1[1]; s1 = 1; }
            if (v0[2] > b0) { b0 = v0[2]; s0 = 2; }
            if (v1[2] > b1) { b1 = v1[2]; s1 = 2; }
            if (v0[3] > b0) { b0 = v0[3]; s0 = 3; }
            if (v1[3] > b1) { b1 = v1[3]; s1 = 3; }
            // interleaved value-only max reductions (independent chains)
            float g0 = b0, g1 = b1;
            #pragma unroll
            for (int m = 32; m >= 1; m >>= 1) {
                g0 = fmaxf(g0, __shfl_xor(g0, m, 64));
                g1 = fmaxf(g1, __shfl_xor(g1, m, 64));
            }
            unsigned long long m0 = __ballot(b0 == g0);
            unsigned long long m1 = __ballot(b1 == g1);
            int wl0 = (int)__builtin_ctzll(m0);
            int wl1 = (int)__builtin_ctzll(m1);
            int ws0 = __shfl(s0, wl0, 64);
            int ws1 = __shfl(s1, wl1, 64);
            if (lane == it) { myidx0 = wl0 * 4 + ws0; myidx1 = wl1 * 4 + ws1; }
            if (lane == wl0) v0[ws0] = -INFINITY;
            if (lane == wl1) v1[ws1] = -INFINITY;
        }
        if (lane < KSEL) {
            idxout[(size_t)row0 * KSEL + lane]       = myidx0;
            idxout[(size_t)(row0 + 1) * KSEL + lane] = myidx1;
        }
        return;
    }

    // ---------------- conv+BN part (one of q/k/v) ----------------
    int bi    = blockIdx.x;              // 0..4607
    int which = bi / 1536;               // 0=q 1=k 2=v
    int rem   = bi % 1536;
    int b     = rem / 192;
    int rem2  = rem % 192;
    int y     = rem2 / 6;
    int sub   = rem2 % 6;
    int chunk = sub >> 1;
    int xc    = sub & 1;
    int x0    = xc * 16;
    int c     = chunk * 256 + threadIdx.x;

    float wl[25];
    const float* wp = w + ((size_t)which * D + c) * 25;
    #pragma unroll
    for (int i = 0; i < 25; i++) wl[i] = wp[i];

    int g = which * D + c;
    float inv = gamma[g] * rsqrtf(var[g] + 1e-5f);
    float sh  = beta[g] - mean[g] * inv;
    if (which == 0) {
        const float scale = 0.03608439182435161f;   // 768^-0.5 folded into q
        inv *= scale; sh *= scale;
    }
    float* dst = (which == 0) ? qw : (which == 1) ? kw : vw;

    const float* xb = x + (size_t)b * 1024 * D + c;

    float a[5][5];
    bool yok[5];
    #pragma unroll
    for (int i = 0; i < 5; i++) {
        int yy = y - 2 + i;
        yok[i] = (yy >= 0 && yy < 32);
        #pragma unroll
        for (int j = 0; j < 5; j++) {
            int xxc = x0 - 2 + j;
            a[i][j] = (yok[i] && xxc >= 0 && xxc < 32)
                      ? xb[(yy * 32 + xxc) * D] : 0.f;
        }
    }

    int head = c / DH, cc = c % DH;
    int i0 = y & 15, A = y >> 4;
    int n = b * HEADS + head;

    #pragma unroll                       // FULL unroll: shifts become renames
    for (int t = 0; t < 16; t++) {
        int xx = x0 + t;
        float s = 0.f;
        #pragma unroll
        for (int i = 0; i < 5; i++)
        #pragma unroll
        for (int j = 0; j < 5; j++)
            s = fmaf(a[i][j], wl[i*5+j], s);
        int j0 = xx & 15, Bq = xx >> 4;
        int win = i0 * 16 + j0, slot = A * 2 + Bq;
        size_t off = (((size_t)n * P2 + win) * 4 + slot) * DH + cc;
        dst[off] = s * inv + sh;
        #pragma unroll
        for (int i = 0; i < 5; i++)
        #pragma unroll
        for (int j = 0; j < 4; j++)
            a[i][j] = a[i][j+1];
        int xn = xx + 3;
        bool xok = (xn < 32);
        #pragma unroll
        for (int i = 0; i < 5; i++) {
            int yy = y - 2 + i;
            a[i][4] = (yok[i] && xok) ? xb[(yy * 32 + xn) * D] : 0.f;
        }
    }
}

// ---------------------------------------------------------------------------
// Kernel 2: attention, all-64-lane balanced (unchanged from round 7).
// ---------------------------------------------------------------------------
__global__ __launch_bounds__(256) void attn_kernel(
    const int*   __restrict__ idxin,  // (32768, 8)
    const float* __restrict__ qw,     // pre-scaled
    const float* __restrict__ kw,
    const float* __restrict__ vw,
    float* __restrict__ out)          // (8,1024,768) fp32
{
    __shared__ float4 vL[4][32 * 13];
    __shared__ float4 qL[4][4 * 13];
    __shared__ float  pL[4][4 * 36];

    int wave = threadIdx.x >> 6;
    int lane = threadIdx.x & 63;
    int B    = blockIdx.x;                 // 8192 blocks
    int n    = (B & 7) * 16 + (B >> 9);    // 0..127 (XCD swizzle)
    int wing = (B >> 3) & 63;
    int win  = wing * 4 + wave;            // 0..255
    int row  = n * P2 + win;
    int b    = n >> 4, head = n & 15;

    float4* vs4 = vL[wave];
    float4* qs4 = qL[wave];
    float*  ps  = pL[wave];

    int l2 = lane & 31, half = lane >> 5;
    int kk = l2 >> 2, tt = l2 & 3;
    int mywin = idxin[row * KSEL + kk];

    const float4* qp = (const float4*)(qw + ((size_t)n * P2 + win) * 192);
    if (lane < 48) {
        int r = lane / 12, c4 = lane % 12;
        qs4[r * 13 + c4] = qp[lane];
    }

    size_t gbase = (((size_t)n * P2 + mywin) * 4 + tt) * DH + half * 24;
    const float4* srcK = (const float4*)(kw + gbase);
    const float4* srcV = (const float4*)(vw + gbase);
    float4 kregh[6];
    #pragma unroll
    for (int j = 0; j < 6; j++) kregh[j] = srcK[j];
    #pragma unroll
    for (int j = 0; j < 6; j++) vs4[l2 * 13 + half * 6 + j] = srcV[j];
    __syncthreads();

    float s4[4];
    #pragma unroll
    for (int r = 0; r < 4; r++) {
        float acc = 0.f;
        #pragma unroll
        for (int j = 0; j < 6; j++) {
            float4 q4 = qs4[r * 13 + half * 6 + j];
            acc = fmaf(q4.x, kregh[j].x, acc);
            acc = fmaf(q4.y, kregh[j].y, acc);
            acc = fmaf(q4.z, kregh[j].z, acc);
            acc = fmaf(q4.w, kregh[j].w, acc);
        }
        s4[r] = acc;
    }
    #pragma unroll
    for (int r = 0; r < 4; r++)
        s4[r] += __shfl_xor(s4[r], 32, 64);

    #pragma unroll
    for (int e = 0; e < 2; e++) {
        int r = 2 * half + e;
        float sv = s4[r];
        float m = sv;
        #pragma unroll
        for (int mm = 16; mm >= 1; mm >>= 1)
            m = fmaxf(m, __shfl_xor(m, mm, 64));
        float p = __expf(sv - m);
        float sum = p;
        #pragma unroll
        for (int mm = 16; mm >= 1; mm >>= 1)
            sum += __shfl_xor(sum, mm, 64);
        ps[r * 36 + l2] = p / sum;
    }
    __syncthreads();

    if (lane < 48) {
        int r = lane / 12, c4 = lane % 12;
        const float4* psv = (const float4*)(ps + r * 36);
        float4 acc = {0.f, 0.f, 0.f, 0.f};
        #pragma unroll
        for (int k2q = 0; k2q < 8; k2q++) {
            float4 p4 = psv[k2q];
            float4 v0 = vs4[(k2q * 4 + 0) * 13 + c4];
            float4 v1 = vs4[(k2q * 4 + 1) * 13 + c4];
            float4 v2 = vs4[(k2q * 4 + 2) * 13 + c4];
            float4 v3 = vs4[(k2q * 4 + 3) * 13 + c4];
            acc.x = fmaf(p4.x, v0.x, acc.x); acc.y = fmaf(p4.x, v0.y, acc.y);
            acc.z = fmaf(p4.x, v0.z, acc.z); acc.w = fmaf(p4.x, v0.w, acc.w);
            acc.x = fmaf(p4.y, v1.x, acc.x); acc.y = fmaf(p4.y, v1.y, acc.y);
            acc.z = fmaf(p4.y, v1.z, acc.z); acc.w = fmaf(p4.y, v1.w, acc.w);
            acc.x = fmaf(p4.z, v2.x, acc.x); acc.y = fmaf(p4.z, v2.y, acc.y);
            acc.z = fmaf(p4.z, v2.z, acc.z); acc.w = fmaf(p4.z, v2.w, acc.w);
            acc.x = fmaf(p4.w, v3.x, acc.x); acc.y = fmaf(p4.w, v3.y, acc.y);
            acc.z = fmaf(p4.w, v3.z, acc.z); acc.w = fmaf(p4.w, v3.w, acc.w);
        }
        int i0 = win >> 4, j0 = win & 15;
        int Aq = r >> 1, Bq = r & 1;
        int rowp = Bq * 16 + i0, colp = Aq * 16 + j0;
        float* op = out + ((size_t)b * 1024 + rowp * 32 + colp) * D
                        + head * DH + c4 * 4;
        *(float4*)op = acc;
    }
}

// ---------------------------------------------------------------------------
// Fallback (zero workspace): fully fused, round-3 version.
// ---------------------------------------------------------------------------
__global__ __launch_bounds__(256) void fused_attn(
    const float* __restrict__ x,
    const float* __restrict__ adjg,
    const float* __restrict__ w,
    const float* __restrict__ gamma,
    const float* __restrict__ beta,
    const float* __restrict__ mean,
    const float* __restrict__ var,
    float* __restrict__ out)
{
    __shared__ float wL[3][25][48];
    __shared__ float bnI[3][48], bnS[3][48];
    __shared__ float qL[4][192];
    __shared__ float vL[4][32 * VSTRIDE];
    __shared__ float pL[4][4 * PSTRIDE];

    int tid  = threadIdx.x;
    int wave = tid >> 6, lane = tid & 63;
    int unit = blockIdx.x * 4 + wave;
    int n    = unit >> 8;
    int win  = unit & 255;
    int b    = n >> 4, head = n & 15;

    for (int j = tid; j < 3600; j += 256) {
        int chunk = j / 1200, rem = j % 1200, t = rem / 48, cc = rem % 48;
        wL[chunk][t][cc] = w[(size_t)chunk * D * 25 + (head * DH + cc) * 25 + t];
    }
    for (int j = tid; j < 144; j += 256) {
        int chunk = j / 48, cc = j % 48;
        int g = chunk * D + head * DH + cc;
        float inv = gamma[g] * rsqrtf(var[g] + 1e-5f);
        bnI[chunk][cc] = inv;
        bnS[chunk][cc] = beta[g] - mean[g] * inv;
    }
    __syncthreads();

    float* qs = qL[wave];
    float* vs = vL[wave];
    float* ps = pL[wave];

    const float* arow = adjg + ((size_t)n * P2 + win) * P2;
    float4 av4 = *(const float4*)(arow + lane * 4);
    float vals[4] = {av4.x, av4.y, av4.z, av4.w};

    int l2 = lane & 31;
    int kk = l2 >> 2, tt = l2 & 3;
    int mywin = 0;
    #pragma unroll
    for (int it = 0; it < KSEL; it++) {
        float bv = vals[0]; int bidx = lane * 4;
        #pragma unroll
        for (int s = 1; s < 4; s++)
            if (vals[s] > bv) { bv = vals[s]; bidx = lane * 4 + s; }
        #pragma unroll
        for (int m = 32; m >= 1; m >>= 1) {
            float ov = __shfl_xor(bv, m, 64);
            int   oi = __shfl_xor(bidx, m, 64);
            if (ov > bv || (ov == bv && oi < bidx)) { bv = ov; bidx = oi; }
        }
        if (kk == it) mywin = bidx;
        #pragma unroll
        for (int s = 0; s < 4; s++)
            if (lane * 4 + s == bidx) vals[s] = -INFINITY;
    }

    const float scale = 0.03608439182435161f;
    int i0 = win >> 4, j0 = win & 15;
    const float* xbh = x + (size_t)b * 1024 * D + head * DH;

    #pragma unroll
    for (int e = 0; e < 3; e++) {
        int idx = lane + 64 * e;
        int r = idx / 48, cc = idx % 48;
        int yq  = (r >> 1) * 16 + i0;
        int xq0 = (r & 1) * 16 + j0;
        float acc = 0.f;
        for (int ty = 0; ty < 5; ty++) {
            int yy = yq + ty - 2;
            if (yy < 0 || yy > 31) continue;
            for (int tx = 0; tx < 5; tx++) {
                int xx = xq0 + tx - 2;
                if (xx < 0 || xx > 31) continue;
                acc = fmaf(xbh[(size_t)(yy * 32 + xx) * D + cc],
                           wL[0][ty * 5 + tx][cc], acc);
            }
        }
        qs[idx] = (acc * bnI[0][cc] + bnS[0][cc]) * scale;
    }

    int half  = lane >> 5;
    int chunk = 1 + half;
    float accv[48];
    {
        int yk  = (tt >> 1) * 16 + (mywin >> 4);
        int xk0 = (tt & 1) * 16 + (mywin & 15);
        #pragma unroll
        for (int cc = 0; cc < 48; cc++) accv[cc] = 0.f;
        for (int ty = 0; ty < 5; ty++) {
            int yy = yk + ty - 2;
            if (yy < 0 || yy > 31) continue;
            for (int tx = 0; tx < 5; tx++) {
                int xx = xk0 + tx - 2;
                if (xx < 0 || xx > 31) continue;
                const float* px = xbh + (size_t)(yy * 32 + xx) * D;
                const float* wt = wL[chunk][ty * 5 + tx];
                #pragma unroll
                for (int c4 = 0; c4 < 12; c4++) {
                    float4 xv = *(const float4*)(px + c4 * 4);
                    accv[c4*4+0] = fmaf(xv.x, wt[c4*4+0], accv[c4*4+0]);
                    accv[c4*4+1] = fmaf(xv.y, wt[c4*4+1], accv[c4*4+1]);
                    accv[c4*4+2] = fmaf(xv.z, wt[c4*4+2], accv[c4*4+2]);
                    accv[c4*4+3] = fmaf(xv.w, wt[c4*4+3], accv[c4*4+3]);
                }
            }
        }
        #pragma unroll
        for (int cc = 0; cc < 48; cc++) {
            float val = accv[cc] * bnI[chunk][cc] + bnS[chunk][cc];
            if (half) vs[l2 * VSTRIDE + cc] = val;
            else      accv[cc] = val;
        }
    }
    __syncthreads();

    if (!half) {
        float s4[4] = {0.f, 0.f, 0.f, 0.f};
        #pragma unroll
        for (int c = 0; c < 48; c++) {
            float kc = accv[c];
            s4[0] = fmaf(qs[c],       kc, s4[0]);
            s4[1] = fmaf(qs[48 + c],  kc, s4[1]);
            s4[2] = fmaf(qs[96 + c],  kc, s4[2]);
            s4[3] = fmaf(qs[144 + c], kc, s4[3]);
        }
        #pragma unroll
        for (int r = 0; r < 4; r++) {
            float m = s4[r];
            #pragma unroll
            for (int mm = 16; mm >= 1; mm >>= 1)
                m = fmaxf(m, __shfl_xor(m, mm, 64));
            float p = __expf(s4[r] - m);
            float sum = p;
            #pragma unroll
            for (int mm = 16; mm >= 1; mm >>= 1)
                sum += __shfl_xor(sum, mm, 64);
            ps[r * PSTRIDE + l2] = p / sum;
        }
    }
    __syncthreads();

    #pragma unroll
    for (int e = 0; e < 3; e++) {
        int idx = lane + 64 * e;
        int r = idx / 48, c = idx % 48;
        float acc = 0.f;
        #pragma unroll
        for (int k2 = 0; k2 < 32; k2++)
            acc = fmaf(ps[r * PSTRIDE + k2], vs[k2 * VSTRIDE + c], acc);
        int Aq = r >> 1, Bq = r & 1;
        int rowp = Bq * 16 + i0, colp = Aq * 16 + j0;
        out[((size_t)b * 1024 + rowp * 32 + colp) * D + head * DH + c] = acc;
    }
}

extern "C" void kernel_launch(void* const* d_in, const int* in_sizes, int n_in,
                              void* d_out, int out_size, void* d_ws, size_t ws_size,
                              hipStream_t stream)
{
    const float* x     = (const float*)d_in[0];
    // d_in[1] = noise (unused by reference)
    const float* adjg  = (const float*)d_in[2];
    const float* w     = (const float*)d_in[3];
    const float* gamma = (const float*)d_in[4];
    const float* beta  = (const float*)d_in[5];
    const float* mean  = (const float*)d_in[6];
    const float* var   = (const float*)d_in[7];
    // d_in[8] = sparsity (=8, compile-time KSEL)

    const size_t NQKV   = (size_t)8 * HEADS * P2 * 4 * DH;   // 6291456 elements
    const size_t NROWS  = (size_t)8 * HEADS * P2;            // 32768
    const size_t need3  = 3 * NQKV * sizeof(float) + NROWS * KSEL * sizeof(int);

    if (ws_size >= need3) {
        float* qw  = (float*)d_ws;
        float* kw  = qw + NQKV;
        float* vw  = kw + NQKV;
        int*   idx = (int*)(vw + NQKV);
        prep_kernel<<<CONV_BLOCKS + TOPK_BLOCKS, 256, 0, stream>>>(
            x, w, gamma, beta, mean, var, adjg, qw, kw, vw, idx);
        attn_kernel<<<8192, 256, 0, stream>>>(idx, qw, kw, vw, (float*)d_out);
    } else {
        fused_attn<<<8192, 256, 0, stream>>>(x, adjg, w, gamma, beta, mean, var,
                                             (float*)d_out);
    }
}